// Round 2
// baseline (396.231 us; speedup 1.0000x reference)
//
#include <hip/hip_runtime.h>

#define T_TOK 2048
#define HID   2048
#define NH    16
#define NKV   2
#define HD    128
#define QDIM  (NH * HD)                 // 2048
#define KVDIM (NKV * HD)                // 256
#define QKVDIM (QDIM + 2 * KVDIM)       // 2560

typedef float          f32x4  __attribute__((ext_vector_type(4)));
typedef unsigned short u16x8  __attribute__((ext_vector_type(8)));
typedef __bf16         bf16x8 __attribute__((ext_vector_type(8)));

__device__ __forceinline__ unsigned short f2bf(float f) {
    unsigned int u = __builtin_bit_cast(unsigned int, f);
    u += 0x7fffu + ((u >> 16) & 1u);   // round-to-nearest-even
    return (unsigned short)(u >> 16);
}

__device__ __forceinline__ f32x4 mfma16(u16x8 a, u16x8 b, f32x4 c) {
    return __builtin_amdgcn_mfma_f32_16x16x32_bf16(
        __builtin_bit_cast(bf16x8, a), __builtin_bit_cast(bf16x8, b), c, 0, 0, 0);
}

// ---------------------------------------------------------------------------
// K1: qkv = hidden @ [Wq;Wk;Wv]^T. 128x128 tile, BK=32, 4 waves (2x2),
// each wave 64x64 = 4x4 MFMA fragments. fp32->bf16 convert in staging.
// ---------------------------------------------------------------------------
__global__ __launch_bounds__(256) void qkv_gemm(
    const float* __restrict__ hidden,
    const float* __restrict__ Wq,
    const float* __restrict__ Wk,
    const float* __restrict__ Wv,
    float* __restrict__ qkv)
{
    __shared__ alignas(16) unsigned short As[128][40];
    __shared__ alignas(16) unsigned short Bs[128][40];

    const int tid  = threadIdx.x;
    const int lane = tid & 63;
    const int w    = tid >> 6;
    const int lg   = lane >> 4, lc = lane & 15;
    const int m0   = blockIdx.y * 128, n0 = blockIdx.x * 128;

    // weight source select (tile-uniform: 2048 and 2304 are multiples of 128? 2304=18*128 yes)
    const float* Wrow; int nloc;
    if (n0 < QDIM)              { Wrow = Wq; nloc = n0; }
    else if (n0 < QDIM + KVDIM) { Wrow = Wk; nloc = n0 - QDIM; }
    else                        { Wrow = Wv; nloc = n0 - QDIM - KVDIM; }

    const int srow = tid >> 1;           // 0..127
    const int scol = (tid & 1) * 16;     // 0 or 16

    const int wr = (w >> 1) * 64, wc = (w & 1) * 64;
    f32x4 acc[4][4] = {};

    for (int kb = 0; kb < HID; kb += 32) {
        __syncthreads();
        {   // stage A tile: 16 fp32 -> bf16 per thread
            const float* s = &hidden[(size_t)(m0 + srow) * HID + kb + scol];
            unsigned short* d = &As[srow][scol];
            #pragma unroll
            for (int i = 0; i < 4; i++) {
                float4 f = *reinterpret_cast<const float4*>(s + i * 4);
                d[i*4+0]=f2bf(f.x); d[i*4+1]=f2bf(f.y);
                d[i*4+2]=f2bf(f.z); d[i*4+3]=f2bf(f.w);
            }
        }
        {   // stage B tile
            const float* s = &Wrow[(size_t)(nloc + srow) * HID + kb + scol];
            unsigned short* d = &Bs[srow][scol];
            #pragma unroll
            for (int i = 0; i < 4; i++) {
                float4 f = *reinterpret_cast<const float4*>(s + i * 4);
                d[i*4+0]=f2bf(f.x); d[i*4+1]=f2bf(f.y);
                d[i*4+2]=f2bf(f.z); d[i*4+3]=f2bf(f.w);
            }
        }
        __syncthreads();

        u16x8 af[4], bf[4];
        #pragma unroll
        for (int mi = 0; mi < 4; mi++)
            af[mi] = *reinterpret_cast<const u16x8*>(&As[wr + mi * 16 + lc][lg * 8]);
        #pragma unroll
        for (int ni = 0; ni < 4; ni++)
            bf[ni] = *reinterpret_cast<const u16x8*>(&Bs[wc + ni * 16 + lc][lg * 8]);
        #pragma unroll
        for (int mi = 0; mi < 4; mi++)
            #pragma unroll
            for (int ni = 0; ni < 4; ni++)
                acc[mi][ni] = mfma16(af[mi], bf[ni], acc[mi][ni]);
    }

    #pragma unroll
    for (int mi = 0; mi < 4; mi++)
        #pragma unroll
        for (int ni = 0; ni < 4; ni++)
            #pragma unroll
            for (int j = 0; j < 4; j++)
                qkv[(size_t)(m0 + wr + mi * 16 + lg * 4 + j) * QKVDIM
                    + n0 + wc + ni * 16 + lc] = acc[mi][ni][j];
}

// ---------------------------------------------------------------------------
// K2: fp32 RoPE on q/k, emit bf16 q_rope/k_rope. One block per token.
// ---------------------------------------------------------------------------
__global__ __launch_bounds__(256) void rope_kernel(
    const float* __restrict__ qkv,
    const int* __restrict__ positions,
    unsigned short* __restrict__ qr,
    unsigned short* __restrict__ kr)
{
    const int t   = blockIdx.x;
    const int tid = threadIdx.x;
    __shared__ float cosv[64], sinv[64];

    if (tid < 64) {
        float invf = expf(-(float)tid * 0.14391156831212787f); // 10000^(-j/64)
        float f = (float)positions[t] * invf;
        cosv[tid] = cosf(f);
        sinv[tid] = sinf(f);
    }
    __syncthreads();

    const float* row = qkv + (size_t)t * QKVDIM;

    for (int i = tid; i < NH * 64; i += 256) {
        int hh = i >> 6, j = i & 63;
        float x1 = row[hh * HD + j];
        float x2 = row[hh * HD + j + 64];
        float c = cosv[j], s = sinv[j];
        qr[(size_t)t * QDIM + hh * HD + j]      = f2bf(x1 * c - x2 * s);
        qr[(size_t)t * QDIM + hh * HD + j + 64] = f2bf(x2 * c + x1 * s);
    }
    if (tid < NKV * 64) {
        int hh = tid >> 6, j = tid & 63;
        float x1 = row[QDIM + hh * HD + j];
        float x2 = row[QDIM + hh * HD + j + 64];
        float c = cosv[j], s = sinv[j];
        kr[(size_t)t * KVDIM + hh * HD + j]      = f2bf(x1 * c - x2 * s);
        kr[(size_t)t * KVDIM + hh * HD + j + 64] = f2bf(x2 * c + x1 * s);
    }
}

// ---------------------------------------------------------------------------
// K2b: V transpose: qkv fp32 [T][...V section] -> vt bf16 [KVDIM][T].
// 64x64 tiles through LDS; coalesced read and write.
// ---------------------------------------------------------------------------
__global__ __launch_bounds__(256) void v_transpose(
    const float* __restrict__ qkv,
    unsigned short* __restrict__ vt)
{
    __shared__ unsigned short tile[64][72];
    const int tid = threadIdx.x;
    const int t0  = blockIdx.x * 64;
    const int d0  = blockIdx.y * 64;

    {
        int r = tid >> 2;            // token row 0..63
        int c = (tid & 3) * 16;      // 0,16,32,48
        const float* src = &qkv[(size_t)(t0 + r) * QKVDIM + QDIM + KVDIM + d0 + c];
        #pragma unroll
        for (int i = 0; i < 4; i++) {
            float4 f = *reinterpret_cast<const float4*>(src + i * 4);
            tile[r][c + i*4 + 0] = f2bf(f.x);
            tile[r][c + i*4 + 1] = f2bf(f.y);
            tile[r][c + i*4 + 2] = f2bf(f.z);
            tile[r][c + i*4 + 3] = f2bf(f.w);
        }
    }
    __syncthreads();
    {
        int dr = tid >> 3;           // 0..31
        int tc = (tid & 7) * 8;      // 0..56
        #pragma unroll
        for (int i = 0; i < 2; i++) {
            int d = dr + i * 32;
            u16x8 ov;
            #pragma unroll
            for (int e = 0; e < 8; e++) ov[e] = tile[tc + e][d];
            *reinterpret_cast<u16x8*>(&vt[(size_t)(d0 + d) * T_TOK + t0 + tc]) = ov;
        }
    }
}

// ---------------------------------------------------------------------------
// K3: causal GQA flash attention. Block = (head, 64-q-row tile), 4 waves,
// each wave owns 16 q rows independently. V consumed transposed (vector
// B-fragment loads, k-contiguous per lane).
// ---------------------------------------------------------------------------
__global__ __launch_bounds__(256) void attn_kernel(
    const unsigned short* __restrict__ q,   // bf16 [T][NH*HD]
    const unsigned short* __restrict__ k,   // bf16 [T][NKV*HD]
    const unsigned short* __restrict__ vt,  // bf16 [KVDIM][T] (transposed)
    unsigned short* __restrict__ o)         // bf16 [T][NH*HD]
{
    __shared__ alignas(16) unsigned short P[4][16][40];  // per-wave, padded

    const int tid  = threadIdx.x;
    const int lane = tid & 63;
    const int w    = tid >> 6;
    const int lg   = lane >> 4, lc = lane & 15;
    const int h    = blockIdx.x >> 5;     // 16 heads
    const int qt   = blockIdx.x & 31;     // 32 q-tiles of 64
    const int q0   = qt * 64 + w * 16;
    const int hk   = h >> 3;              // GQA group = 8
    const float scale = 0.08838834764831845f;  // 128^-0.5

    const unsigned short* vbase = vt + (size_t)hk * HD * T_TOK;

    u16x8 qf[4];
    #pragma unroll
    for (int dc = 0; dc < 4; dc++)
        qf[dc] = *reinterpret_cast<const u16x8*>(
            &q[(size_t)(q0 + lc) * QDIM + h * HD + dc * 32 + lg * 8]);

    float m[4], ell[4];
    #pragma unroll
    for (int j = 0; j < 4; j++) { m[j] = -1e30f; ell[j] = 0.f; }
    f32x4 oacc[8] = {};

    const int kend = q0 + 16;
    for (int kb = 0; kb < kend; kb += 32) {
        float sc[2][4];
        #pragma unroll
        for (int c2 = 0; c2 < 2; c2++) {
            const int kc = kb + c2 * 16;
            f32x4 s = {0.f, 0.f, 0.f, 0.f};
            #pragma unroll
            for (int dc = 0; dc < 4; dc++) {
                u16x8 kf = *reinterpret_cast<const u16x8*>(
                    &k[(size_t)(kc + lc) * KVDIM + hk * HD + dc * 32 + lg * 8]);
                s = mfma16(qf[dc], kf, s);
            }
            #pragma unroll
            for (int j = 0; j < 4; j++) {
                const int qrow = q0 + lg * 4 + j;
                const int krow = kc + lc;
                sc[c2][j] = (krow <= qrow) ? s[j] * scale : -1e30f;
            }
        }
        float alpha[4];
        #pragma unroll
        for (int j = 0; j < 4; j++) {
            float t = fmaxf(sc[0][j], sc[1][j]);
            #pragma unroll
            for (int off = 8; off >= 1; off >>= 1)
                t = fmaxf(t, __shfl_xor(t, off));
            float mn = fmaxf(m[j], t);
            alpha[j] = __expf(m[j] - mn);
            m[j] = mn;
        }
        float rs[4] = {0.f, 0.f, 0.f, 0.f};
        #pragma unroll
        for (int c2 = 0; c2 < 2; c2++)
            #pragma unroll
            for (int j = 0; j < 4; j++) {
                float p = __expf(sc[c2][j] - m[j]);
                rs[j] += p;
                P[w][lg * 4 + j][c2 * 16 + lc] = f2bf(p);
            }
        #pragma unroll
        for (int j = 0; j < 4; j++) {
            float t = rs[j];
            #pragma unroll
            for (int off = 8; off >= 1; off >>= 1)
                t += __shfl_xor(t, off);
            ell[j] = ell[j] * alpha[j] + t;
        }
        #pragma unroll
        for (int nt = 0; nt < 8; nt++)
            #pragma unroll
            for (int j = 0; j < 4; j++)
                oacc[nt][j] *= alpha[j];

        // per-wave LDS write->read: drain LDS queue, pin schedule (rule #18)
        asm volatile("s_waitcnt lgkmcnt(0)" ::: "memory");
        __builtin_amdgcn_sched_barrier(0);

        u16x8 pf = *reinterpret_cast<const u16x8*>(&P[w][lc][lg * 8]);

        #pragma unroll
        for (int nt = 0; nt < 8; nt++) {
            u16x8 vf = *reinterpret_cast<const u16x8*>(
                &vbase[(size_t)(nt * 16 + lc) * T_TOK + kb + lg * 8]);
            oacc[nt] = mfma16(pf, vf, oacc[nt]);
        }
    }

    #pragma unroll
    for (int nt = 0; nt < 8; nt++)
        #pragma unroll
        for (int j = 0; j < 4; j++) {
            float val = oacc[nt][j] / ell[j];
            o[(size_t)(q0 + lg * 4 + j) * QDIM + h * HD + nt * 16 + lc] = f2bf(val);
        }
}

// ---------------------------------------------------------------------------
// K4: out = attn(bf16) @ Wo^T. 128x128 tile, BK=32, same geometry as K1.
// ---------------------------------------------------------------------------
__global__ __launch_bounds__(256) void out_gemm(
    const unsigned short* __restrict__ attn,  // bf16 [T][QDIM]
    const float* __restrict__ Wo,             // [HID][QDIM]
    float* __restrict__ out)                  // [T][HID]
{
    __shared__ alignas(16) unsigned short As[128][40];
    __shared__ alignas(16) unsigned short Bs[128][40];

    const int tid  = threadIdx.x;
    const int lane = tid & 63;
    const int w    = tid >> 6;
    const int lg   = lane >> 4, lc = lane & 15;
    const int m0   = blockIdx.y * 128, n0 = blockIdx.x * 128;

    const int srow = tid >> 1;
    const int scol = (tid & 1) * 16;

    const int wr = (w >> 1) * 64, wc = (w & 1) * 64;
    f32x4 acc[4][4] = {};

    for (int kb = 0; kb < QDIM; kb += 32) {
        __syncthreads();
        {   // A already bf16: two 16B copies
            const unsigned short* s = &attn[(size_t)(m0 + srow) * QDIM + kb + scol];
            *reinterpret_cast<u16x8*>(&As[srow][scol])     = *reinterpret_cast<const u16x8*>(s);
            *reinterpret_cast<u16x8*>(&As[srow][scol + 8]) = *reinterpret_cast<const u16x8*>(s + 8);
        }
        {   // B fp32 -> bf16
            const float* s = &Wo[(size_t)(n0 + srow) * QDIM + kb + scol];
            unsigned short* d = &Bs[srow][scol];
            #pragma unroll
            for (int i = 0; i < 4; i++) {
                float4 f = *reinterpret_cast<const float4*>(s + i * 4);
                d[i*4+0]=f2bf(f.x); d[i*4+1]=f2bf(f.y);
                d[i*4+2]=f2bf(f.z); d[i*4+3]=f2bf(f.w);
            }
        }
        __syncthreads();

        u16x8 af[4], bf[4];
        #pragma unroll
        for (int mi = 0; mi < 4; mi++)
            af[mi] = *reinterpret_cast<const u16x8*>(&As[wr + mi * 16 + lc][lg * 8]);
        #pragma unroll
        for (int ni = 0; ni < 4; ni++)
            bf[ni] = *reinterpret_cast<const u16x8*>(&Bs[wc + ni * 16 + lc][lg * 8]);
        #pragma unroll
        for (int mi = 0; mi < 4; mi++)
            #pragma unroll
            for (int ni = 0; ni < 4; ni++)
                acc[mi][ni] = mfma16(af[mi], bf[ni], acc[mi][ni]);
    }

    #pragma unroll
    for (int mi = 0; mi < 4; mi++)
        #pragma unroll
        for (int ni = 0; ni < 4; ni++)
            #pragma unroll
            for (int j = 0; j < 4; j++)
                out[(size_t)(m0 + wr + mi * 16 + lg * 4 + j) * HID
                    + n0 + wc + ni * 16 + lc] = acc[mi][ni][j];
}

// ---------------------------------------------------------------------------
extern "C" void kernel_launch(void* const* d_in, const int* in_sizes, int n_in,
                              void* d_out, int out_size, void* d_ws, size_t ws_size,
                              hipStream_t stream) {
    const float* hidden    = (const float*)d_in[0];
    const int*   positions = (const int*)d_in[1];
    const float* Wq        = (const float*)d_in[2];
    const float* Wk        = (const float*)d_in[3];
    const float* Wv        = (const float*)d_in[4];
    const float* Wo        = (const float*)d_in[5];
    float*       out       = (float*)d_out;

    char* ws = (char*)d_ws;
    float*          qkv = (float*)(ws);                                // 20971520 B
    unsigned short* qr  = (unsigned short*)(ws + 20971520);            // 8388608 B
    unsigned short* kr  = (unsigned short*)(ws + 20971520 + 8388608);  // 1048576 B
    unsigned short* vt  = (unsigned short*)(ws + 20971520 + 9437184);  // 1048576 B [KVDIM][T]
    unsigned short* att = (unsigned short*)(ws + 20971520 + 10485760); // 8388608 B

    qkv_gemm<<<dim3(QKVDIM / 128, T_TOK / 128), 256, 0, stream>>>(hidden, Wq, Wk, Wv, qkv);
    rope_kernel<<<T_TOK, 256, 0, stream>>>(qkv, positions, qr, kr);
    v_transpose<<<dim3(T_TOK / 64, KVDIM / 64), 256, 0, stream>>>(qkv, vt);
    attn_kernel<<<NH * (T_TOK / 64), 256, 0, stream>>>(qr, kr, vt, att);
    out_gemm<<<dim3(HID / 128, T_TOK / 128), 256, 0, stream>>>(att, Wo, out);
}

// Round 3
// 272.269 us; speedup vs baseline: 1.4553x; 1.4553x over previous
//
#include <hip/hip_runtime.h>

#define T_TOK 2048
#define HID   2048
#define NH    16
#define NKV   2
#define HD    128
#define QDIM  (NH * HD)                 // 2048
#define KVDIM (NKV * HD)                // 256
#define QKVDIM (QDIM + 2 * KVDIM)       // 2560

typedef float          f32x4  __attribute__((ext_vector_type(4)));
typedef unsigned short u16x8  __attribute__((ext_vector_type(8)));
typedef __bf16         bf16x8 __attribute__((ext_vector_type(8)));

__device__ __forceinline__ unsigned short f2bf(float f) {
    unsigned int u = __builtin_bit_cast(unsigned int, f);
    u += 0x7fffu + ((u >> 16) & 1u);   // round-to-nearest-even
    return (unsigned short)(u >> 16);
}

__device__ __forceinline__ f32x4 mfma16(u16x8 a, u16x8 b, f32x4 c) {
    return __builtin_amdgcn_mfma_f32_16x16x32_bf16(
        __builtin_bit_cast(bf16x8, a), __builtin_bit_cast(bf16x8, b), c, 0, 0, 0);
}

// ---------------------------------------------------------------------------
// K1: qkv = hidden @ [Wq;Wk;Wv]^T   (fp32 in, fp32 out, bf16 MFMA internally)
// 64x64 tile, BK=32, 4 waves (2x2), each wave 32x32 = 2x2 MFMA fragments.
// (round-1 measured-good config; 1280 blocks = 5/CU)
// ---------------------------------------------------------------------------
__global__ __launch_bounds__(256) void qkv_gemm(
    const float* __restrict__ hidden,
    const float* __restrict__ Wq,
    const float* __restrict__ Wk,
    const float* __restrict__ Wv,
    float* __restrict__ qkv)
{
    __shared__ alignas(16) unsigned short As[64][40];
    __shared__ alignas(16) unsigned short Bs[64][40];

    const int tid  = threadIdx.x;
    const int lane = tid & 63;
    const int w    = tid >> 6;
    const int lg   = lane >> 4, lc = lane & 15;
    const int m0   = blockIdx.y * 64, n0 = blockIdx.x * 64;

    const float* Wrow; int nloc;
    if (n0 < QDIM)              { Wrow = Wq; nloc = n0; }
    else if (n0 < QDIM + KVDIM) { Wrow = Wk; nloc = n0 - QDIM; }
    else                        { Wrow = Wv; nloc = n0 - QDIM - KVDIM; }

    const int srow = tid >> 2;           // 0..63
    const int scol = (tid & 3) * 8;      // 0,8,16,24

    const int wr = (w >> 1) * 32, wc = (w & 1) * 32;
    f32x4 acc[2][2] = {};

    for (int kb = 0; kb < HID; kb += 32) {
        __syncthreads();
        {
            const float* s = &hidden[(size_t)(m0 + srow) * HID + kb + scol];
            float4 a0 = *reinterpret_cast<const float4*>(s);
            float4 a1 = *reinterpret_cast<const float4*>(s + 4);
            unsigned short* d = &As[srow][scol];
            d[0]=f2bf(a0.x); d[1]=f2bf(a0.y); d[2]=f2bf(a0.z); d[3]=f2bf(a0.w);
            d[4]=f2bf(a1.x); d[5]=f2bf(a1.y); d[6]=f2bf(a1.z); d[7]=f2bf(a1.w);
        }
        {
            const float* s = &Wrow[(size_t)(nloc + srow) * HID + kb + scol];
            float4 b0 = *reinterpret_cast<const float4*>(s);
            float4 b1 = *reinterpret_cast<const float4*>(s + 4);
            unsigned short* d = &Bs[srow][scol];
            d[0]=f2bf(b0.x); d[1]=f2bf(b0.y); d[2]=f2bf(b0.z); d[3]=f2bf(b0.w);
            d[4]=f2bf(b1.x); d[5]=f2bf(b1.y); d[6]=f2bf(b1.z); d[7]=f2bf(b1.w);
        }
        __syncthreads();

        u16x8 af0 = *reinterpret_cast<const u16x8*>(&As[wr + lc][lg * 8]);
        u16x8 af1 = *reinterpret_cast<const u16x8*>(&As[wr + 16 + lc][lg * 8]);
        u16x8 bf0 = *reinterpret_cast<const u16x8*>(&Bs[wc + lc][lg * 8]);
        u16x8 bf1 = *reinterpret_cast<const u16x8*>(&Bs[wc + 16 + lc][lg * 8]);
        acc[0][0] = mfma16(af0, bf0, acc[0][0]);
        acc[0][1] = mfma16(af0, bf1, acc[0][1]);
        acc[1][0] = mfma16(af1, bf0, acc[1][0]);
        acc[1][1] = mfma16(af1, bf1, acc[1][1]);
    }

    #pragma unroll
    for (int mi = 0; mi < 2; mi++)
        #pragma unroll
        for (int ni = 0; ni < 2; ni++)
            #pragma unroll
            for (int j = 0; j < 4; j++)
                qkv[(size_t)(m0 + wr + mi * 16 + lg * 4 + j) * QKVDIM
                    + n0 + wc + ni * 16 + lc] = acc[mi][ni][j];
}

// ---------------------------------------------------------------------------
// K2: fp32 RoPE on q/k, emit bf16 q_rope/k_rope. One block per token.
// ---------------------------------------------------------------------------
__global__ __launch_bounds__(256) void rope_kernel(
    const float* __restrict__ qkv,
    const int* __restrict__ positions,
    unsigned short* __restrict__ qr,
    unsigned short* __restrict__ kr)
{
    const int t   = blockIdx.x;
    const int tid = threadIdx.x;
    __shared__ float cosv[64], sinv[64];

    if (tid < 64) {
        float invf = expf(-(float)tid * 0.14391156831212787f); // 10000^(-j/64)
        float f = (float)positions[t] * invf;
        cosv[tid] = cosf(f);
        sinv[tid] = sinf(f);
    }
    __syncthreads();

    const float* row = qkv + (size_t)t * QKVDIM;

    for (int i = tid; i < NH * 64; i += 256) {
        int hh = i >> 6, j = i & 63;
        float x1 = row[hh * HD + j];
        float x2 = row[hh * HD + j + 64];
        float c = cosv[j], s = sinv[j];
        qr[(size_t)t * QDIM + hh * HD + j]      = f2bf(x1 * c - x2 * s);
        qr[(size_t)t * QDIM + hh * HD + j + 64] = f2bf(x2 * c + x1 * s);
    }
    if (tid < NKV * 64) {
        int hh = tid >> 6, j = tid & 63;
        float x1 = row[QDIM + hh * HD + j];
        float x2 = row[QDIM + hh * HD + j + 64];
        float c = cosv[j], s = sinv[j];
        kr[(size_t)t * KVDIM + hh * HD + j]      = f2bf(x1 * c - x2 * s);
        kr[(size_t)t * KVDIM + hh * HD + j + 64] = f2bf(x2 * c + x1 * s);
    }
}

// ---------------------------------------------------------------------------
// K2b: V transpose: qkv fp32 V-section -> vt bf16 [KVDIM][T].
// ---------------------------------------------------------------------------
__global__ __launch_bounds__(256) void v_transpose(
    const float* __restrict__ qkv,
    unsigned short* __restrict__ vt)
{
    __shared__ unsigned short tile[64][72];
    const int tid = threadIdx.x;
    const int t0  = blockIdx.x * 64;
    const int d0  = blockIdx.y * 64;

    {
        int r = tid >> 2;
        int c = (tid & 3) * 16;
        const float* src = &qkv[(size_t)(t0 + r) * QKVDIM + QDIM + KVDIM + d0 + c];
        #pragma unroll
        for (int i = 0; i < 4; i++) {
            float4 f = *reinterpret_cast<const float4*>(src + i * 4);
            tile[r][c + i*4 + 0] = f2bf(f.x);
            tile[r][c + i*4 + 1] = f2bf(f.y);
            tile[r][c + i*4 + 2] = f2bf(f.z);
            tile[r][c + i*4 + 3] = f2bf(f.w);
        }
    }
    __syncthreads();
    {
        int dr = tid >> 3;
        int tc = (tid & 7) * 8;
        #pragma unroll
        for (int i = 0; i < 2; i++) {
            int d = dr + i * 32;
            u16x8 ov;
            #pragma unroll
            for (int e = 0; e < 8; e++) ov[e] = tile[tc + e][d];
            *reinterpret_cast<u16x8*>(&vt[(size_t)(d0 + d) * T_TOK + t0 + tc]) = ov;
        }
    }
}

// ---------------------------------------------------------------------------
// K3: causal GQA flash attention. ONE WAVE PER BLOCK (64 threads), each wave
// owns 16 q rows; KV-block = 64 keys/iter. Blocks LPT-ordered: longest
// q-chunks (most keys) dispatched first -> near-optimal CU packing.
// ---------------------------------------------------------------------------
__global__ __launch_bounds__(64) void attn_kernel(
    const unsigned short* __restrict__ q,   // bf16 [T][NH*HD]
    const unsigned short* __restrict__ k,   // bf16 [T][NKV*HD]
    const unsigned short* __restrict__ vt,  // bf16 [KVDIM][T] (transposed)
    unsigned short* __restrict__ o)         // bf16 [T][NH*HD]
{
    __shared__ alignas(16) unsigned short P[16][72];   // 16 rows x 64 keys (+8 pad)

    const int lane = threadIdx.x;            // 0..63
    const int lg   = lane >> 4, lc = lane & 15;
    const int b    = blockIdx.x;
    const int h    = b & 15;                 // 16 heads
    const int c    = 127 - (b >> 4);         // q-chunk, LPT: longest first
    const int q0   = c * 16;
    const int hk   = h >> 3;                 // GQA group = 8
    const float scale = 0.08838834764831845f;  // 128^-0.5

    const unsigned short* vbase = vt + (size_t)hk * HD * T_TOK;

    u16x8 qf[4];
    #pragma unroll
    for (int dc = 0; dc < 4; dc++)
        qf[dc] = *reinterpret_cast<const u16x8*>(
            &q[(size_t)(q0 + lc) * QDIM + h * HD + dc * 32 + lg * 8]);

    float m[4], ell[4];
    #pragma unroll
    for (int j = 0; j < 4; j++) { m[j] = -1e30f; ell[j] = 0.f; }
    f32x4 oacc[8] = {};

    const int kend = q0 + 16;
    for (int kb = 0; kb < kend; kb += 64) {
        float sc[4][4];
        #pragma unroll
        for (int c4 = 0; c4 < 4; c4++) {
            const int kc = kb + c4 * 16;
            f32x4 s = {0.f, 0.f, 0.f, 0.f};
            #pragma unroll
            for (int dc = 0; dc < 4; dc++) {
                u16x8 kf = *reinterpret_cast<const u16x8*>(
                    &k[(size_t)(kc + lc) * KVDIM + hk * HD + dc * 32 + lg * 8]);
                s = mfma16(qf[dc], kf, s);
            }
            #pragma unroll
            for (int j = 0; j < 4; j++) {
                const int qrow = q0 + lg * 4 + j;
                const int krow = kc + lc;
                sc[c4][j] = (krow <= qrow) ? s[j] * scale : -1e30f;
            }
        }
        // online softmax over 64 keys
        float alpha[4];
        #pragma unroll
        for (int j = 0; j < 4; j++) {
            float t = fmaxf(fmaxf(sc[0][j], sc[1][j]), fmaxf(sc[2][j], sc[3][j]));
            #pragma unroll
            for (int off = 8; off >= 1; off >>= 1)
                t = fmaxf(t, __shfl_xor(t, off));
            float mn = fmaxf(m[j], t);
            alpha[j] = __expf(m[j] - mn);
            m[j] = mn;
        }
        float rs[4] = {0.f, 0.f, 0.f, 0.f};
        #pragma unroll
        for (int c4 = 0; c4 < 4; c4++)
            #pragma unroll
            for (int j = 0; j < 4; j++) {
                float pv = __expf(sc[c4][j] - m[j]);
                rs[j] += pv;
                P[lg * 4 + j][c4 * 16 + lc] = f2bf(pv);
            }
        #pragma unroll
        for (int j = 0; j < 4; j++) {
            float t = rs[j];
            #pragma unroll
            for (int off = 8; off >= 1; off >>= 1)
                t += __shfl_xor(t, off);
            ell[j] = ell[j] * alpha[j] + t;
        }
        #pragma unroll
        for (int nt = 0; nt < 8; nt++)
            #pragma unroll
            for (int j = 0; j < 4; j++)
                oacc[nt][j] *= alpha[j];

        // single-wave LDS write->read: drain LDS queue, pin schedule (rule #18)
        asm volatile("s_waitcnt lgkmcnt(0)" ::: "memory");
        __builtin_amdgcn_sched_barrier(0);

        u16x8 pf0 = *reinterpret_cast<const u16x8*>(&P[lc][lg * 8]);
        u16x8 pf1 = *reinterpret_cast<const u16x8*>(&P[lc][32 + lg * 8]);

        #pragma unroll
        for (int nt = 0; nt < 8; nt++) {
            u16x8 vf0 = *reinterpret_cast<const u16x8*>(
                &vbase[(size_t)(nt * 16 + lc) * T_TOK + kb + lg * 8]);
            u16x8 vf1 = *reinterpret_cast<const u16x8*>(
                &vbase[(size_t)(nt * 16 + lc) * T_TOK + kb + 32 + lg * 8]);
            oacc[nt] = mfma16(pf0, vf0, oacc[nt]);
            oacc[nt] = mfma16(pf1, vf1, oacc[nt]);
        }
    }

    #pragma unroll
    for (int nt = 0; nt < 8; nt++)
        #pragma unroll
        for (int j = 0; j < 4; j++) {
            float val = oacc[nt][j] / ell[j];
            o[(size_t)(q0 + lg * 4 + j) * QDIM + h * HD + nt * 16 + lc] = f2bf(val);
        }
}

// ---------------------------------------------------------------------------
// K4: out = attn(bf16) @ Wo^T. 64x64 tile (round-1 config).
// ---------------------------------------------------------------------------
__global__ __launch_bounds__(256) void out_gemm(
    const unsigned short* __restrict__ attn,  // bf16 [T][QDIM]
    const float* __restrict__ Wo,             // [HID][QDIM]
    float* __restrict__ out)                  // [T][HID]
{
    __shared__ alignas(16) unsigned short As[64][40];
    __shared__ alignas(16) unsigned short Bs[64][40];

    const int tid  = threadIdx.x;
    const int lane = tid & 63;
    const int w    = tid >> 6;
    const int lg   = lane >> 4, lc = lane & 15;
    const int m0   = blockIdx.y * 64, n0 = blockIdx.x * 64;

    const int srow = tid >> 2;
    const int scol = (tid & 3) * 8;

    const int wr = (w >> 1) * 32, wc = (w & 1) * 32;
    f32x4 acc[2][2] = {};

    for (int kb = 0; kb < QDIM; kb += 32) {
        __syncthreads();
        {
            u16x8 a = *reinterpret_cast<const u16x8*>(
                &attn[(size_t)(m0 + srow) * QDIM + kb + scol]);
            *reinterpret_cast<u16x8*>(&As[srow][scol]) = a;
        }
        {
            const float* s = &Wo[(size_t)(n0 + srow) * QDIM + kb + scol];
            float4 b0 = *reinterpret_cast<const float4*>(s);
            float4 b1 = *reinterpret_cast<const float4*>(s + 4);
            unsigned short* d = &Bs[srow][scol];
            d[0]=f2bf(b0.x); d[1]=f2bf(b0.y); d[2]=f2bf(b0.z); d[3]=f2bf(b0.w);
            d[4]=f2bf(b1.x); d[5]=f2bf(b1.y); d[6]=f2bf(b1.z); d[7]=f2bf(b1.w);
        }
        __syncthreads();

        u16x8 af0 = *reinterpret_cast<const u16x8*>(&As[wr + lc][lg * 8]);
        u16x8 af1 = *reinterpret_cast<const u16x8*>(&As[wr + 16 + lc][lg * 8]);
        u16x8 bf0 = *reinterpret_cast<const u16x8*>(&Bs[wc + lc][lg * 8]);
        u16x8 bf1 = *reinterpret_cast<const u16x8*>(&Bs[wc + 16 + lc][lg * 8]);
        acc[0][0] = mfma16(af0, bf0, acc[0][0]);
        acc[0][1] = mfma16(af0, bf1, acc[0][1]);
        acc[1][0] = mfma16(af1, bf0, acc[1][0]);
        acc[1][1] = mfma16(af1, bf1, acc[1][1]);
    }

    #pragma unroll
    for (int mi = 0; mi < 2; mi++)
        #pragma unroll
        for (int ni = 0; ni < 2; ni++)
            #pragma unroll
            for (int j = 0; j < 4; j++)
                out[(size_t)(m0 + wr + mi * 16 + lg * 4 + j) * HID
                    + n0 + wc + ni * 16 + lc] = acc[mi][ni][j];
}

// ---------------------------------------------------------------------------
extern "C" void kernel_launch(void* const* d_in, const int* in_sizes, int n_in,
                              void* d_out, int out_size, void* d_ws, size_t ws_size,
                              hipStream_t stream) {
    const float* hidden    = (const float*)d_in[0];
    const int*   positions = (const int*)d_in[1];
    const float* Wq        = (const float*)d_in[2];
    const float* Wk        = (const float*)d_in[3];
    const float* Wv        = (const float*)d_in[4];
    const float* Wo        = (const float*)d_in[5];
    float*       out       = (float*)d_out;

    char* ws = (char*)d_ws;
    float*          qkv = (float*)(ws);                                // 20971520 B
    unsigned short* qr  = (unsigned short*)(ws + 20971520);            // 8388608 B
    unsigned short* kr  = (unsigned short*)(ws + 20971520 + 8388608);  // 1048576 B
    unsigned short* vt  = (unsigned short*)(ws + 20971520 + 9437184);  // 1048576 B [KVDIM][T]
    unsigned short* att = (unsigned short*)(ws + 20971520 + 10485760); // 8388608 B

    qkv_gemm<<<dim3(QKVDIM / 64, T_TOK / 64), 256, 0, stream>>>(hidden, Wq, Wk, Wv, qkv);
    rope_kernel<<<T_TOK, 256, 0, stream>>>(qkv, positions, qr, kr);
    v_transpose<<<dim3(T_TOK / 64, KVDIM / 64), 256, 0, stream>>>(qkv, vt);
    attn_kernel<<<NH * (T_TOK / 16), 64, 0, stream>>>(qr, kr, vt, att);
    out_gemm<<<dim3(HID / 64, T_TOK / 64), 256, 0, stream>>>(att, Wo, out);
}

// Round 4
// 205.712 us; speedup vs baseline: 1.9261x; 1.3235x over previous
//
#include <hip/hip_runtime.h>

#define T_TOK 2048
#define HID   2048
#define NH    16
#define NKV   2
#define HD    128
#define QDIM  (NH * HD)                 // 2048
#define KVDIM (NKV * HD)                // 256
#define QKVDIM (QDIM + 2 * KVDIM)       // 2560

typedef float          f32x4  __attribute__((ext_vector_type(4)));
typedef unsigned short u16x8  __attribute__((ext_vector_type(8)));
typedef __bf16         bf16x8 __attribute__((ext_vector_type(8)));

__device__ __forceinline__ unsigned short f2bf(float f) {
    unsigned int u = __builtin_bit_cast(unsigned int, f);
    u += 0x7fffu + ((u >> 16) & 1u);   // round-to-nearest-even
    return (unsigned short)(u >> 16);
}

__device__ __forceinline__ f32x4 mfma16(u16x8 a, u16x8 b, f32x4 c) {
    return __builtin_amdgcn_mfma_f32_16x16x32_bf16(
        __builtin_bit_cast(bf16x8, a), __builtin_bit_cast(bf16x8, b), c, 0, 0, 0);
}

// ---------------------------------------------------------------------------
// K1: qkv = hidden @ [Wq;Wk;Wv]^T. 64x64 tile, BK=32 (round-1/3 config).
// ---------------------------------------------------------------------------
__global__ __launch_bounds__(256) void qkv_gemm(
    const float* __restrict__ hidden,
    const float* __restrict__ Wq,
    const float* __restrict__ Wk,
    const float* __restrict__ Wv,
    float* __restrict__ qkv)
{
    __shared__ alignas(16) unsigned short As[64][40];
    __shared__ alignas(16) unsigned short Bs[64][40];

    const int tid  = threadIdx.x;
    const int lane = tid & 63;
    const int w    = tid >> 6;
    const int lg   = lane >> 4, lc = lane & 15;
    const int m0   = blockIdx.y * 64, n0 = blockIdx.x * 64;

    const float* Wrow; int nloc;
    if (n0 < QDIM)              { Wrow = Wq; nloc = n0; }
    else if (n0 < QDIM + KVDIM) { Wrow = Wk; nloc = n0 - QDIM; }
    else                        { Wrow = Wv; nloc = n0 - QDIM - KVDIM; }

    const int srow = tid >> 2;
    const int scol = (tid & 3) * 8;

    const int wr = (w >> 1) * 32, wc = (w & 1) * 32;
    f32x4 acc[2][2] = {};

    for (int kb = 0; kb < HID; kb += 32) {
        __syncthreads();
        {
            const float* s = &hidden[(size_t)(m0 + srow) * HID + kb + scol];
            float4 a0 = *reinterpret_cast<const float4*>(s);
            float4 a1 = *reinterpret_cast<const float4*>(s + 4);
            unsigned short* d = &As[srow][scol];
            d[0]=f2bf(a0.x); d[1]=f2bf(a0.y); d[2]=f2bf(a0.z); d[3]=f2bf(a0.w);
            d[4]=f2bf(a1.x); d[5]=f2bf(a1.y); d[6]=f2bf(a1.z); d[7]=f2bf(a1.w);
        }
        {
            const float* s = &Wrow[(size_t)(nloc + srow) * HID + kb + scol];
            float4 b0 = *reinterpret_cast<const float4*>(s);
            float4 b1 = *reinterpret_cast<const float4*>(s + 4);
            unsigned short* d = &Bs[srow][scol];
            d[0]=f2bf(b0.x); d[1]=f2bf(b0.y); d[2]=f2bf(b0.z); d[3]=f2bf(b0.w);
            d[4]=f2bf(b1.x); d[5]=f2bf(b1.y); d[6]=f2bf(b1.z); d[7]=f2bf(b1.w);
        }
        __syncthreads();

        u16x8 af0 = *reinterpret_cast<const u16x8*>(&As[wr + lc][lg * 8]);
        u16x8 af1 = *reinterpret_cast<const u16x8*>(&As[wr + 16 + lc][lg * 8]);
        u16x8 bf0 = *reinterpret_cast<const u16x8*>(&Bs[wc + lc][lg * 8]);
        u16x8 bf1 = *reinterpret_cast<const u16x8*>(&Bs[wc + 16 + lc][lg * 8]);
        acc[0][0] = mfma16(af0, bf0, acc[0][0]);
        acc[0][1] = mfma16(af0, bf1, acc[0][1]);
        acc[1][0] = mfma16(af1, bf0, acc[1][0]);
        acc[1][1] = mfma16(af1, bf1, acc[1][1]);
    }

    #pragma unroll
    for (int mi = 0; mi < 2; mi++)
        #pragma unroll
        for (int ni = 0; ni < 2; ni++)
            #pragma unroll
            for (int j = 0; j < 4; j++)
                qkv[(size_t)(m0 + wr + mi * 16 + lg * 4 + j) * QKVDIM
                    + n0 + wc + ni * 16 + lc] = acc[mi][ni][j];
}

// ---------------------------------------------------------------------------
// K2: fp32 RoPE on q/k, emit bf16 q_rope/k_rope. One block per token.
// ---------------------------------------------------------------------------
__global__ __launch_bounds__(256) void rope_kernel(
    const float* __restrict__ qkv,
    const int* __restrict__ positions,
    unsigned short* __restrict__ qr,
    unsigned short* __restrict__ kr)
{
    const int t   = blockIdx.x;
    const int tid = threadIdx.x;
    __shared__ float cosv[64], sinv[64];

    if (tid < 64) {
        float invf = expf(-(float)tid * 0.14391156831212787f); // 10000^(-j/64)
        float f = (float)positions[t] * invf;
        cosv[tid] = cosf(f);
        sinv[tid] = sinf(f);
    }
    __syncthreads();

    const float* row = qkv + (size_t)t * QKVDIM;

    for (int i = tid; i < NH * 64; i += 256) {
        int hh = i >> 6, j = i & 63;
        float x1 = row[hh * HD + j];
        float x2 = row[hh * HD + j + 64];
        float c = cosv[j], s = sinv[j];
        qr[(size_t)t * QDIM + hh * HD + j]      = f2bf(x1 * c - x2 * s);
        qr[(size_t)t * QDIM + hh * HD + j + 64] = f2bf(x2 * c + x1 * s);
    }
    if (tid < NKV * 64) {
        int hh = tid >> 6, j = tid & 63;
        float x1 = row[QDIM + hh * HD + j];
        float x2 = row[QDIM + hh * HD + j + 64];
        float c = cosv[j], s = sinv[j];
        kr[(size_t)t * KVDIM + hh * HD + j]      = f2bf(x1 * c - x2 * s);
        kr[(size_t)t * KVDIM + hh * HD + j + 64] = f2bf(x2 * c + x1 * s);
    }
}

// ---------------------------------------------------------------------------
// K2b: V transpose: qkv fp32 V-section -> vt bf16 [KVDIM][T].
// ---------------------------------------------------------------------------
__global__ __launch_bounds__(256) void v_transpose(
    const float* __restrict__ qkv,
    unsigned short* __restrict__ vt)
{
    __shared__ unsigned short tile[64][72];
    const int tid = threadIdx.x;
    const int t0  = blockIdx.x * 64;
    const int d0  = blockIdx.y * 64;

    {
        int r = tid >> 2;
        int c = (tid & 3) * 16;
        const float* src = &qkv[(size_t)(t0 + r) * QKVDIM + QDIM + KVDIM + d0 + c];
        #pragma unroll
        for (int i = 0; i < 4; i++) {
            float4 f = *reinterpret_cast<const float4*>(src + i * 4);
            tile[r][c + i*4 + 0] = f2bf(f.x);
            tile[r][c + i*4 + 1] = f2bf(f.y);
            tile[r][c + i*4 + 2] = f2bf(f.z);
            tile[r][c + i*4 + 3] = f2bf(f.w);
        }
    }
    __syncthreads();
    {
        int dr = tid >> 3;
        int tc = (tid & 7) * 8;
        #pragma unroll
        for (int i = 0; i < 2; i++) {
            int d = dr + i * 32;
            u16x8 ov;
            #pragma unroll
            for (int e = 0; e < 8; e++) ov[e] = tile[tc + e][d];
            *reinterpret_cast<u16x8*>(&vt[(size_t)(d0 + d) * T_TOK + t0 + tc]) = ov;
        }
    }
}

// ---------------------------------------------------------------------------
// K3: causal GQA flash attention. 4-wave blocks (64 q rows, one head),
// K/V tiles staged in LDS via global_load_lds (linear dest, pre-swizzled
// global source; XOR-swizzled ds_read — rule #21). KV-block = 64 keys.
// LPT order: largest q-tiles dispatched first.
// ---------------------------------------------------------------------------
__global__ __launch_bounds__(256) void attn_kernel(
    const unsigned short* __restrict__ q,   // bf16 [T][NH*HD]
    const unsigned short* __restrict__ k,   // bf16 [T][NKV*HD]
    const unsigned short* __restrict__ vt,  // bf16 [KVDIM][T] (transposed)
    unsigned short* __restrict__ o)         // bf16 [T][NH*HD]
{
    __shared__ alignas(16) unsigned short Ks[64 * 128];   // 16 KB, 256 B rows, swizzled
    __shared__ alignas(16) unsigned short Vs[128 * 64];   // 16 KB, 128 B rows, swizzled
    __shared__ alignas(16) unsigned short P[4][16][72];   // per-wave P, padded

    const int tid  = threadIdx.x;
    const int lane = tid & 63;
    const int w    = tid >> 6;
    const int lg   = lane >> 4, lc = lane & 15;
    const int b    = blockIdx.x;
    const int h    = b & 15;                 // 16 heads
    const int tile = 31 - (b >> 4);          // LPT: longest first
    const int q0   = tile * 64 + w * 16;
    const int hk   = h >> 3;                 // GQA group = 8
    const float scale = 0.08838834764831845f;  // 128^-0.5
    const int xr   = (lc & 7) << 4;          // read-side XOR swizzle (bytes)

    // staging geometry (per-lane, loop-invariant)
    const int krow_l = (lane >> 4);                     // K: row within 4-row chunk
    const int kgS    = (lane & 15);                     // K: dest granule
    const int vrow_l = (lane >> 3);                     // V: row within 8-row chunk
    const int vgS    = (lane & 7);                      // V: dest granule

    u16x8 qf[4];
    #pragma unroll
    for (int dc = 0; dc < 4; dc++)
        qf[dc] = *reinterpret_cast<const u16x8*>(
            &q[(size_t)(q0 + lc) * QDIM + h * HD + dc * 32 + lg * 8]);

    float m[4], ell[4];
    #pragma unroll
    for (int j = 0; j < 4; j++) { m[j] = -1e30f; ell[j] = 0.f; }
    f32x4 oacc[8] = {};

    const int nt = tile + 1;
    for (int t = 0; t < nt; ++t) {
        const int kb = t * 64;

        __syncthreads();   // all waves done reading previous Ks/Vs

        // ---- stage K tile [64 rows][128 d] (this wave: 4 x 1KB chunks) ----
        #pragma unroll
        for (int ci = 0; ci < 4; ci++) {
            const int chunk = w * 4 + ci;
            const int row   = chunk * 4 + krow_l;            // 0..63
            const int gS    = kgS ^ (row & 7);               // pre-swizzled source granule
            const unsigned short* gp =
                &k[(size_t)(kb + row) * KVDIM + hk * HD + gS * 8];
            __builtin_amdgcn_global_load_lds(
                (const __attribute__((address_space(1))) void*)gp,
                (__attribute__((address_space(3))) void*)(&Ks[chunk * 512]),
                16, 0, 0);
        }
        // ---- stage V^T tile [128 d][64 tok] (this wave: 4 x 1KB chunks) ----
        #pragma unroll
        for (int ci = 0; ci < 4; ci++) {
            const int chunk = w * 4 + ci;
            const int dr    = chunk * 8 + vrow_l;            // 0..127
            const int gS    = vgS ^ (dr & 7);
            const unsigned short* gp =
                &vt[(size_t)(hk * HD + dr) * T_TOK + kb + gS * 8];
            __builtin_amdgcn_global_load_lds(
                (const __attribute__((address_space(1))) void*)gp,
                (__attribute__((address_space(3))) void*)(&Vs[chunk * 512]),
                16, 0, 0);
        }

        asm volatile("s_waitcnt vmcnt(0)" ::: "memory");
        __syncthreads();   // staged tiles visible to all waves

        // ---- QK^T (from swizzled LDS) ----
        const char* KsB = (const char*)Ks;
        const char* VsB = (const char*)Vs;
        float sc[4][4];
        #pragma unroll
        for (int c4 = 0; c4 < 4; c4++) {
            const int row = c4 * 16 + lc;
            f32x4 s = {0.f, 0.f, 0.f, 0.f};
            #pragma unroll
            for (int dc = 0; dc < 4; dc++) {
                u16x8 kf = *reinterpret_cast<const u16x8*>(
                    KsB + row * 256 + ((dc * 64 + lg * 16) ^ xr));
                s = mfma16(qf[dc], kf, s);
            }
            #pragma unroll
            for (int j = 0; j < 4; j++) {
                const int qrow = q0 + lg * 4 + j;
                const int krow = kb + c4 * 16 + lc;
                sc[c4][j] = (krow <= qrow) ? s[j] * scale : -1e30f;
            }
        }
        // ---- online softmax over 64 keys ----
        float alpha[4];
        #pragma unroll
        for (int j = 0; j < 4; j++) {
            float tmx = fmaxf(fmaxf(sc[0][j], sc[1][j]), fmaxf(sc[2][j], sc[3][j]));
            #pragma unroll
            for (int off = 8; off >= 1; off >>= 1)
                tmx = fmaxf(tmx, __shfl_xor(tmx, off));
            float mn = fmaxf(m[j], tmx);
            alpha[j] = __expf(m[j] - mn);
            m[j] = mn;
        }
        float rs[4] = {0.f, 0.f, 0.f, 0.f};
        #pragma unroll
        for (int c4 = 0; c4 < 4; c4++)
            #pragma unroll
            for (int j = 0; j < 4; j++) {
                float pv = __expf(sc[c4][j] - m[j]);
                rs[j] += pv;
                P[w][lg * 4 + j][c4 * 16 + lc] = f2bf(pv);
            }
        #pragma unroll
        for (int j = 0; j < 4; j++) {
            float ts = rs[j];
            #pragma unroll
            for (int off = 8; off >= 1; off >>= 1)
                ts += __shfl_xor(ts, off);
            ell[j] = ell[j] * alpha[j] + ts;
        }
        #pragma unroll
        for (int d8 = 0; d8 < 8; d8++)
            #pragma unroll
            for (int j = 0; j < 4; j++)
                oacc[d8][j] *= alpha[j];

        // per-wave LDS write->read: drain LDS queue, pin schedule (rule #18)
        asm volatile("s_waitcnt lgkmcnt(0)" ::: "memory");
        __builtin_amdgcn_sched_barrier(0);

        u16x8 pf0 = *reinterpret_cast<const u16x8*>(&P[w][lc][lg * 8]);
        u16x8 pf1 = *reinterpret_cast<const u16x8*>(&P[w][lc][32 + lg * 8]);

        // ---- PV (V^T from swizzled LDS) ----
        #pragma unroll
        for (int d8 = 0; d8 < 8; d8++) {
            const int drow = d8 * 16 + lc;
            u16x8 vf0 = *reinterpret_cast<const u16x8*>(
                VsB + drow * 128 + ((lg * 16) ^ xr));
            u16x8 vf1 = *reinterpret_cast<const u16x8*>(
                VsB + drow * 128 + ((lg * 16 + 64) ^ xr));
            oacc[d8] = mfma16(pf0, vf0, oacc[d8]);
            oacc[d8] = mfma16(pf1, vf1, oacc[d8]);
        }
    }

    #pragma unroll
    for (int d8 = 0; d8 < 8; d8++)
        #pragma unroll
        for (int j = 0; j < 4; j++) {
            float val = oacc[d8][j] / ell[j];
            o[(size_t)(q0 + lg * 4 + j) * QDIM + h * HD + d8 * 16 + lc] = f2bf(val);
        }
}

// ---------------------------------------------------------------------------
// K4: out = attn(bf16) @ Wo^T. 64x64 tile (round-1/3 config).
// ---------------------------------------------------------------------------
__global__ __launch_bounds__(256) void out_gemm(
    const unsigned short* __restrict__ attn,  // bf16 [T][QDIM]
    const float* __restrict__ Wo,             // [HID][QDIM]
    float* __restrict__ out)                  // [T][HID]
{
    __shared__ alignas(16) unsigned short As[64][40];
    __shared__ alignas(16) unsigned short Bs[64][40];

    const int tid  = threadIdx.x;
    const int lane = tid & 63;
    const int w    = tid >> 6;
    const int lg   = lane >> 4, lc = lane & 15;
    const int m0   = blockIdx.y * 64, n0 = blockIdx.x * 64;

    const int srow = tid >> 2;
    const int scol = (tid & 3) * 8;

    const int wr = (w >> 1) * 32, wc = (w & 1) * 32;
    f32x4 acc[2][2] = {};

    for (int kb = 0; kb < QDIM; kb += 32) {
        __syncthreads();
        {
            u16x8 a = *reinterpret_cast<const u16x8*>(
                &attn[(size_t)(m0 + srow) * QDIM + kb + scol]);
            *reinterpret_cast<u16x8*>(&As[srow][scol]) = a;
        }
        {
            const float* s = &Wo[(size_t)(n0 + srow) * QDIM + kb + scol];
            float4 b0 = *reinterpret_cast<const float4*>(s);
            float4 b1 = *reinterpret_cast<const float4*>(s + 4);
            unsigned short* d = &Bs[srow][scol];
            d[0]=f2bf(b0.x); d[1]=f2bf(b0.y); d[2]=f2bf(b0.z); d[3]=f2bf(b0.w);
            d[4]=f2bf(b1.x); d[5]=f2bf(b1.y); d[6]=f2bf(b1.z); d[7]=f2bf(b1.w);
        }
        __syncthreads();

        u16x8 af0 = *reinterpret_cast<const u16x8*>(&As[wr + lc][lg * 8]);
        u16x8 af1 = *reinterpret_cast<const u16x8*>(&As[wr + 16 + lc][lg * 8]);
        u16x8 bf0 = *reinterpret_cast<const u16x8*>(&Bs[wc + lc][lg * 8]);
        u16x8 bf1 = *reinterpret_cast<const u16x8*>(&Bs[wc + 16 + lc][lg * 8]);
        acc[0][0] = mfma16(af0, bf0, acc[0][0]);
        acc[0][1] = mfma16(af0, bf1, acc[0][1]);
        acc[1][0] = mfma16(af1, bf0, acc[1][0]);
        acc[1][1] = mfma16(af1, bf1, acc[1][1]);
    }

    #pragma unroll
    for (int mi = 0; mi < 2; mi++)
        #pragma unroll
        for (int ni = 0; ni < 2; ni++)
            #pragma unroll
            for (int j = 0; j < 4; j++)
                out[(size_t)(m0 + wr + mi * 16 + lg * 4 + j) * HID
                    + n0 + wc + ni * 16 + lc] = acc[mi][ni][j];
}

// ---------------------------------------------------------------------------
extern "C" void kernel_launch(void* const* d_in, const int* in_sizes, int n_in,
                              void* d_out, int out_size, void* d_ws, size_t ws_size,
                              hipStream_t stream) {
    const float* hidden    = (const float*)d_in[0];
    const int*   positions = (const int*)d_in[1];
    const float* Wq        = (const float*)d_in[2];
    const float* Wk        = (const float*)d_in[3];
    const float* Wv        = (const float*)d_in[4];
    const float* Wo        = (const float*)d_in[5];
    float*       out       = (float*)d_out;

    char* ws = (char*)d_ws;
    float*          qkv = (float*)(ws);                                // 20971520 B
    unsigned short* qr  = (unsigned short*)(ws + 20971520);            // 8388608 B
    unsigned short* kr  = (unsigned short*)(ws + 20971520 + 8388608);  // 1048576 B
    unsigned short* vt  = (unsigned short*)(ws + 20971520 + 9437184);  // 1048576 B [KVDIM][T]
    unsigned short* att = (unsigned short*)(ws + 20971520 + 10485760); // 8388608 B

    qkv_gemm<<<dim3(QKVDIM / 64, T_TOK / 64), 256, 0, stream>>>(hidden, Wq, Wk, Wv, qkv);
    rope_kernel<<<T_TOK, 256, 0, stream>>>(qkv, positions, qr, kr);
    v_transpose<<<dim3(T_TOK / 64, KVDIM / 64), 256, 0, stream>>>(qkv, vt);
    attn_kernel<<<NH * (T_TOK / 64), 256, 0, stream>>>(qr, kr, vt, att);
    out_gemm<<<dim3(HID / 64, T_TOK / 64), 256, 0, stream>>>(att, Wo, out);
}

// Round 5
// 176.240 us; speedup vs baseline: 2.2482x; 1.1672x over previous
//
#include <hip/hip_runtime.h>

#define T_TOK 2048
#define HID   2048
#define NH    16
#define NKV   2
#define HD    128
#define QDIM  (NH * HD)                 // 2048
#define KVDIM (NKV * HD)                // 256
#define QKVDIM (QDIM + 2 * KVDIM)       // 2560

typedef float          f32x4  __attribute__((ext_vector_type(4)));
typedef unsigned short u16x8  __attribute__((ext_vector_type(8)));
typedef __bf16         bf16x8 __attribute__((ext_vector_type(8)));

__device__ __forceinline__ unsigned short f2bf(float f) {
    unsigned int u = __builtin_bit_cast(unsigned int, f);
    u += 0x7fffu + ((u >> 16) & 1u);   // round-to-nearest-even
    return (unsigned short)(u >> 16);
}

__device__ __forceinline__ f32x4 mfma16(u16x8 a, u16x8 b, f32x4 c) {
    return __builtin_amdgcn_mfma_f32_16x16x32_bf16(
        __builtin_bit_cast(bf16x8, a), __builtin_bit_cast(bf16x8, b), c, 0, 0, 0);
}

// ---------------------------------------------------------------------------
// K0: convert all fp32 operands to bf16 once (memory-bound pass).
// Segments (blocks of 2048 elems): hidden[2048] Wq[2048] Wk[256] Wv[256] Wo[2048]
// ---------------------------------------------------------------------------
__global__ __launch_bounds__(256) void pack_bf16_all(
    const float* __restrict__ hidden, const float* __restrict__ Wq,
    const float* __restrict__ Wk, const float* __restrict__ Wv,
    const float* __restrict__ Wo,
    unsigned short* __restrict__ hb, unsigned short* __restrict__ Wf,
    unsigned short* __restrict__ Wob)
{
    const int b = blockIdx.x;
    const float* src; unsigned short* dst; size_t off;
    if      (b < 2048) { src = hidden; dst = hb;            off = (size_t)b * 2048; }
    else if (b < 4096) { src = Wq;     dst = Wf;            off = (size_t)(b - 2048) * 2048; }
    else if (b < 4352) { src = Wk;     dst = Wf + 4194304;  off = (size_t)(b - 4096) * 2048; }
    else if (b < 4608) { src = Wv;     dst = Wf + 4718592;  off = (size_t)(b - 4352) * 2048; }
    else               { src = Wo;     dst = Wob;           off = (size_t)(b - 4608) * 2048; }

    const size_t i = off + threadIdx.x * 8;
    float4 f0 = *reinterpret_cast<const float4*>(src + i);
    float4 f1 = *reinterpret_cast<const float4*>(src + i + 4);
    u16x8 o;
    o[0]=f2bf(f0.x); o[1]=f2bf(f0.y); o[2]=f2bf(f0.z); o[3]=f2bf(f0.w);
    o[4]=f2bf(f1.x); o[5]=f2bf(f1.y); o[6]=f2bf(f1.z); o[7]=f2bf(f1.w);
    *reinterpret_cast<u16x8*>(dst + i) = o;
}

// ---------------------------------------------------------------------------
// K1: generic bf16 GEMM  C[M][NC] += A[M][K] @ B[N][K]^T  (fp32 out).
// m97 structure: 128x128 tile, BK=64, global_load_lds width-16 staging
// (linear LDS dest, XOR-pre-swizzled global source; same XOR on ds_read —
// rule #21). 4 waves, each 64x64 = 4x4 frags. 32 MFMA / 16 ds_read_b128
// per wave per K-step.
// ---------------------------------------------------------------------------
__global__ __launch_bounds__(256) void gemm_bf16(
    const unsigned short* __restrict__ A,   // bf16 [M][K]
    const unsigned short* __restrict__ B,   // bf16 [N][K]
    float* __restrict__ C,                  // fp32 [M][NC]
    int K, int NC)
{
    __shared__ alignas(16) unsigned short As[128 * 64];  // [row][64 elems] linear
    __shared__ alignas(16) unsigned short Bs[128 * 64];

    const int tid  = threadIdx.x;
    const int lane = tid & 63;
    const int w    = tid >> 6;
    const int lg   = lane >> 4, lc = lane & 15;
    const int m0   = blockIdx.y * 128, n0 = blockIdx.x * 128;

    // staging geometry: per global_load_lds, wave writes 1KB = 8 rows x 128B.
    const int rowL = lane >> 3;                 // row within 8-row chunk
    const int gS   = (lane & 7) ^ rowL;         // pre-swizzled source granule
    const int wr   = (w >> 1) * 64, wc = (w & 1) * 64;

    f32x4 acc[4][4] = {};

    for (int kb = 0; kb < K; kb += 64) {
        __syncthreads();   // previous compute done reading LDS
        #pragma unroll
        for (int ci = 0; ci < 4; ci++) {
            const int chunk = w * 4 + ci;       // 0..15
            const int row   = chunk * 8 + rowL; // 0..127
            const unsigned short* gpA = &A[(size_t)(m0 + row) * K + kb + gS * 8];
            __builtin_amdgcn_global_load_lds(
                (const __attribute__((address_space(1))) void*)gpA,
                (__attribute__((address_space(3))) void*)(&As[chunk * 512]),
                16, 0, 0);
            const unsigned short* gpB = &B[(size_t)(n0 + row) * K + kb + gS * 8];
            __builtin_amdgcn_global_load_lds(
                (const __attribute__((address_space(1))) void*)gpB,
                (__attribute__((address_space(3))) void*)(&Bs[chunk * 512]),
                16, 0, 0);
        }
        asm volatile("s_waitcnt vmcnt(0)" ::: "memory");
        __syncthreads();   // staged tile visible to all waves

        #pragma unroll
        for (int kk = 0; kk < 2; kk++) {
            u16x8 af[4], bf[4];
            #pragma unroll
            for (int mi = 0; mi < 4; mi++) {
                const int r = wr + mi * 16 + lc;
                const int g = (kk * 4 + lg) ^ (lc & 7);
                af[mi] = *reinterpret_cast<const u16x8*>(&As[r * 64 + g * 8]);
            }
            #pragma unroll
            for (int ni = 0; ni < 4; ni++) {
                const int r = wc + ni * 16 + lc;
                const int g = (kk * 4 + lg) ^ (lc & 7);
                bf[ni] = *reinterpret_cast<const u16x8*>(&Bs[r * 64 + g * 8]);
            }
            #pragma unroll
            for (int mi = 0; mi < 4; mi++)
                #pragma unroll
                for (int ni = 0; ni < 4; ni++)
                    acc[mi][ni] = mfma16(af[mi], bf[ni], acc[mi][ni]);
        }
    }

    #pragma unroll
    for (int mi = 0; mi < 4; mi++)
        #pragma unroll
        for (int ni = 0; ni < 4; ni++)
            #pragma unroll
            for (int j = 0; j < 4; j++)
                C[(size_t)(m0 + wr + mi * 16 + lg * 4 + j) * NC
                  + n0 + wc + ni * 16 + lc] = acc[mi][ni][j];
}

// ---------------------------------------------------------------------------
// K2: fp32 RoPE on q/k, emit bf16 q_rope/k_rope. One block per token.
// ---------------------------------------------------------------------------
__global__ __launch_bounds__(256) void rope_kernel(
    const float* __restrict__ qkv,
    const int* __restrict__ positions,
    unsigned short* __restrict__ qr,
    unsigned short* __restrict__ kr)
{
    const int t   = blockIdx.x;
    const int tid = threadIdx.x;
    __shared__ float cosv[64], sinv[64];

    if (tid < 64) {
        float invf = expf(-(float)tid * 0.14391156831212787f); // 10000^(-j/64)
        float f = (float)positions[t] * invf;
        cosv[tid] = cosf(f);
        sinv[tid] = sinf(f);
    }
    __syncthreads();

    const float* row = qkv + (size_t)t * QKVDIM;

    for (int i = tid; i < NH * 64; i += 256) {
        int hh = i >> 6, j = i & 63;
        float x1 = row[hh * HD + j];
        float x2 = row[hh * HD + j + 64];
        float c = cosv[j], s = sinv[j];
        qr[(size_t)t * QDIM + hh * HD + j]      = f2bf(x1 * c - x2 * s);
        qr[(size_t)t * QDIM + hh * HD + j + 64] = f2bf(x2 * c + x1 * s);
    }
    if (tid < NKV * 64) {
        int hh = tid >> 6, j = tid & 63;
        float x1 = row[QDIM + hh * HD + j];
        float x2 = row[QDIM + hh * HD + j + 64];
        float c = cosv[j], s = sinv[j];
        kr[(size_t)t * KVDIM + hh * HD + j]      = f2bf(x1 * c - x2 * s);
        kr[(size_t)t * KVDIM + hh * HD + j + 64] = f2bf(x2 * c + x1 * s);
    }
}

// ---------------------------------------------------------------------------
// K2b: V transpose: qkv fp32 V-section -> vt bf16 [KVDIM][T].
// ---------------------------------------------------------------------------
__global__ __launch_bounds__(256) void v_transpose(
    const float* __restrict__ qkv,
    unsigned short* __restrict__ vt)
{
    __shared__ unsigned short tile[64][72];
    const int tid = threadIdx.x;
    const int t0  = blockIdx.x * 64;
    const int d0  = blockIdx.y * 64;

    {
        int r = tid >> 2;
        int c = (tid & 3) * 16;
        const float* src = &qkv[(size_t)(t0 + r) * QKVDIM + QDIM + KVDIM + d0 + c];
        #pragma unroll
        for (int i = 0; i < 4; i++) {
            float4 f = *reinterpret_cast<const float4*>(src + i * 4);
            tile[r][c + i*4 + 0] = f2bf(f.x);
            tile[r][c + i*4 + 1] = f2bf(f.y);
            tile[r][c + i*4 + 2] = f2bf(f.z);
            tile[r][c + i*4 + 3] = f2bf(f.w);
        }
    }
    __syncthreads();
    {
        int dr = tid >> 3;
        int tc = (tid & 7) * 8;
        #pragma unroll
        for (int i = 0; i < 2; i++) {
            int d = dr + i * 32;
            u16x8 ov;
            #pragma unroll
            for (int e = 0; e < 8; e++) ov[e] = tile[tc + e][d];
            *reinterpret_cast<u16x8*>(&vt[(size_t)(d0 + d) * T_TOK + t0 + tc]) = ov;
        }
    }
}

// ---------------------------------------------------------------------------
// K3: causal GQA flash attention (round-4 structure, unchanged).
// ---------------------------------------------------------------------------
__global__ __launch_bounds__(256) void attn_kernel(
    const unsigned short* __restrict__ q,   // bf16 [T][NH*HD]
    const unsigned short* __restrict__ k,   // bf16 [T][NKV*HD]
    const unsigned short* __restrict__ vt,  // bf16 [KVDIM][T] (transposed)
    unsigned short* __restrict__ o)         // bf16 [T][NH*HD]
{
    __shared__ alignas(16) unsigned short Ks[64 * 128];
    __shared__ alignas(16) unsigned short Vs[128 * 64];
    __shared__ alignas(16) unsigned short P[4][16][72];

    const int tid  = threadIdx.x;
    const int lane = tid & 63;
    const int w    = tid >> 6;
    const int lg   = lane >> 4, lc = lane & 15;
    const int b    = blockIdx.x;
    const int h    = b & 15;
    const int tile = 31 - (b >> 4);          // LPT: longest first
    const int q0   = tile * 64 + w * 16;
    const int hk   = h >> 3;
    const float scale = 0.08838834764831845f;
    const int xr   = (lc & 7) << 4;

    const int krow_l = (lane >> 4);
    const int kgS    = (lane & 15);
    const int vrow_l = (lane >> 3);
    const int vgS    = (lane & 7);

    u16x8 qf[4];
    #pragma unroll
    for (int dc = 0; dc < 4; dc++)
        qf[dc] = *reinterpret_cast<const u16x8*>(
            &q[(size_t)(q0 + lc) * QDIM + h * HD + dc * 32 + lg * 8]);

    float m[4], ell[4];
    #pragma unroll
    for (int j = 0; j < 4; j++) { m[j] = -1e30f; ell[j] = 0.f; }
    f32x4 oacc[8] = {};

    const int nt = tile + 1;
    for (int t = 0; t < nt; ++t) {
        const int kb = t * 64;

        __syncthreads();

        #pragma unroll
        for (int ci = 0; ci < 4; ci++) {
            const int chunk = w * 4 + ci;
            const int row   = chunk * 4 + krow_l;
            const int gS    = kgS ^ (row & 7);
            const unsigned short* gp =
                &k[(size_t)(kb + row) * KVDIM + hk * HD + gS * 8];
            __builtin_amdgcn_global_load_lds(
                (const __attribute__((address_space(1))) void*)gp,
                (__attribute__((address_space(3))) void*)(&Ks[chunk * 512]),
                16, 0, 0);
        }
        #pragma unroll
        for (int ci = 0; ci < 4; ci++) {
            const int chunk = w * 4 + ci;
            const int dr    = chunk * 8 + vrow_l;
            const int gS    = vgS ^ (dr & 7);
            const unsigned short* gp =
                &vt[(size_t)(hk * HD + dr) * T_TOK + kb + gS * 8];
            __builtin_amdgcn_global_load_lds(
                (const __attribute__((address_space(1))) void*)gp,
                (__attribute__((address_space(3))) void*)(&Vs[chunk * 512]),
                16, 0, 0);
        }

        asm volatile("s_waitcnt vmcnt(0)" ::: "memory");
        __syncthreads();

        const char* KsB = (const char*)Ks;
        const char* VsB = (const char*)Vs;
        float sc[4][4];
        #pragma unroll
        for (int c4 = 0; c4 < 4; c4++) {
            const int row = c4 * 16 + lc;
            f32x4 s = {0.f, 0.f, 0.f, 0.f};
            #pragma unroll
            for (int dc = 0; dc < 4; dc++) {
                u16x8 kf = *reinterpret_cast<const u16x8*>(
                    KsB + row * 256 + ((dc * 64 + lg * 16) ^ xr));
                s = mfma16(qf[dc], kf, s);
            }
            #pragma unroll
            for (int j = 0; j < 4; j++) {
                const int qrow = q0 + lg * 4 + j;
                const int krow = kb + c4 * 16 + lc;
                sc[c4][j] = (krow <= qrow) ? s[j] * scale : -1e30f;
            }
        }
        float alpha[4];
        #pragma unroll
        for (int j = 0; j < 4; j++) {
            float tmx = fmaxf(fmaxf(sc[0][j], sc[1][j]), fmaxf(sc[2][j], sc[3][j]));
            #pragma unroll
            for (int off = 8; off >= 1; off >>= 1)
                tmx = fmaxf(tmx, __shfl_xor(tmx, off));
            float mn = fmaxf(m[j], tmx);
            alpha[j] = __expf(m[j] - mn);
            m[j] = mn;
        }
        float rs[4] = {0.f, 0.f, 0.f, 0.f};
        #pragma unroll
        for (int c4 = 0; c4 < 4; c4++)
            #pragma unroll
            for (int j = 0; j < 4; j++) {
                float pv = __expf(sc[c4][j] - m[j]);
                rs[j] += pv;
                P[w][lg * 4 + j][c4 * 16 + lc] = f2bf(pv);
            }
        #pragma unroll
        for (int j = 0; j < 4; j++) {
            float ts = rs[j];
            #pragma unroll
            for (int off = 8; off >= 1; off >>= 1)
                ts += __shfl_xor(ts, off);
            ell[j] = ell[j] * alpha[j] + ts;
        }
        #pragma unroll
        for (int d8 = 0; d8 < 8; d8++)
            #pragma unroll
            for (int j = 0; j < 4; j++)
                oacc[d8][j] *= alpha[j];

        asm volatile("s_waitcnt lgkmcnt(0)" ::: "memory");
        __builtin_amdgcn_sched_barrier(0);

        u16x8 pf0 = *reinterpret_cast<const u16x8*>(&P[w][lc][lg * 8]);
        u16x8 pf1 = *reinterpret_cast<const u16x8*>(&P[w][lc][32 + lg * 8]);

        #pragma unroll
        for (int d8 = 0; d8 < 8; d8++) {
            const int drow = d8 * 16 + lc;
            u16x8 vf0 = *reinterpret_cast<const u16x8*>(
                VsB + drow * 128 + ((lg * 16) ^ xr));
            u16x8 vf1 = *reinterpret_cast<const u16x8*>(
                VsB + drow * 128 + ((lg * 16 + 64) ^ xr));
            oacc[d8] = mfma16(pf0, vf0, oacc[d8]);
            oacc[d8] = mfma16(pf1, vf1, oacc[d8]);
        }
    }

    #pragma unroll
    for (int d8 = 0; d8 < 8; d8++)
        #pragma unroll
        for (int j = 0; j < 4; j++) {
            float val = oacc[d8][j] / ell[j];
            o[(size_t)(q0 + lg * 4 + j) * QDIM + h * HD + d8 * 16 + lc] = f2bf(val);
        }
}

// ---------------------------------------------------------------------------
extern "C" void kernel_launch(void* const* d_in, const int* in_sizes, int n_in,
                              void* d_out, int out_size, void* d_ws, size_t ws_size,
                              hipStream_t stream) {
    const float* hidden    = (const float*)d_in[0];
    const int*   positions = (const int*)d_in[1];
    const float* Wq        = (const float*)d_in[2];
    const float* Wk        = (const float*)d_in[3];
    const float* Wv        = (const float*)d_in[4];
    const float* Wo        = (const float*)d_in[5];
    float*       out       = (float*)d_out;

    char* ws = (char*)d_ws;
    float*          qkv = (float*)(ws);                     // 20971520 B
    unsigned short* qr  = (unsigned short*)(ws + 20971520); // 8388608 B
    unsigned short* kr  = (unsigned short*)(ws + 29360128); // 1048576 B
    unsigned short* vt  = (unsigned short*)(ws + 30408704); // 1048576 B
    unsigned short* att = (unsigned short*)(ws + 31457280); // 8388608 B
    unsigned short* hb  = (unsigned short*)(ws + 39845888); // 8388608 B  bf16 hidden
    unsigned short* Wf  = (unsigned short*)(ws + 48234496); // 10485760 B bf16 [Wq;Wk;Wv]
    unsigned short* Wob = (unsigned short*)(ws + 58720256); // 8388608 B  bf16 Wo
    // total 67108864 B = 64 MB

    pack_bf16_all<<<6656, 256, 0, stream>>>(hidden, Wq, Wk, Wv, Wo, hb, Wf, Wob);
    gemm_bf16<<<dim3(QKVDIM / 128, T_TOK / 128), 256, 0, stream>>>(hb, Wf, qkv, HID, QKVDIM);
    rope_kernel<<<T_TOK, 256, 0, stream>>>(qkv, positions, qr, kr);
    v_transpose<<<dim3(T_TOK / 64, KVDIM / 64), 256, 0, stream>>>(qkv, vt);
    attn_kernel<<<NH * (T_TOK / 64), 256, 0, stream>>>(qr, kr, vt, att);
    gemm_bf16<<<dim3(HID / 128, T_TOK / 128), 256, 0, stream>>>(att, Wob, out, QDIM, HID);
}

// Round 6
// 159.894 us; speedup vs baseline: 2.4781x; 1.1022x over previous
//
#include <hip/hip_runtime.h>

#define T_TOK 2048
#define HID   2048
#define NH    16
#define NKV   2
#define HD    128
#define QDIM  (NH * HD)                 // 2048
#define KVDIM (NKV * HD)                // 256
#define QKVDIM (QDIM + 2 * KVDIM)       // 2560

typedef float          f32x4  __attribute__((ext_vector_type(4)));
typedef unsigned short u16x8  __attribute__((ext_vector_type(8)));
typedef __bf16         bf16x8 __attribute__((ext_vector_type(8)));

__device__ __forceinline__ unsigned short f2bf(float f) {
    unsigned int u = __builtin_bit_cast(unsigned int, f);
    u += 0x7fffu + ((u >> 16) & 1u);   // round-to-nearest-even
    return (unsigned short)(u >> 16);
}

__device__ __forceinline__ f32x4 mfma16(u16x8 a, u16x8 b, f32x4 c) {
    return __builtin_amdgcn_mfma_f32_16x16x32_bf16(
        __builtin_bit_cast(bf16x8, a), __builtin_bit_cast(bf16x8, b), c, 0, 0, 0);
}

// ---------------------------------------------------------------------------
// K0: convert all fp32 operands to bf16 once (memory-bound pass).
// ---------------------------------------------------------------------------
__global__ __launch_bounds__(256) void pack_bf16_all(
    const float* __restrict__ hidden, const float* __restrict__ Wq,
    const float* __restrict__ Wk, const float* __restrict__ Wv,
    const float* __restrict__ Wo,
    unsigned short* __restrict__ hb, unsigned short* __restrict__ Wf,
    unsigned short* __restrict__ Wob)
{
    const int b = blockIdx.x;
    const float* src; unsigned short* dst; size_t off;
    if      (b < 2048) { src = hidden; dst = hb;            off = (size_t)b * 2048; }
    else if (b < 4096) { src = Wq;     dst = Wf;            off = (size_t)(b - 2048) * 2048; }
    else if (b < 4352) { src = Wk;     dst = Wf + 4194304;  off = (size_t)(b - 4096) * 2048; }
    else if (b < 4608) { src = Wv;     dst = Wf + 4718592;  off = (size_t)(b - 4352) * 2048; }
    else               { src = Wo;     dst = Wob;           off = (size_t)(b - 4608) * 2048; }

    const size_t i = off + threadIdx.x * 8;
    float4 f0 = *reinterpret_cast<const float4*>(src + i);
    float4 f1 = *reinterpret_cast<const float4*>(src + i + 4);
    u16x8 o;
    o[0]=f2bf(f0.x); o[1]=f2bf(f0.y); o[2]=f2bf(f0.z); o[3]=f2bf(f0.w);
    o[4]=f2bf(f1.x); o[5]=f2bf(f1.y); o[6]=f2bf(f1.z); o[7]=f2bf(f1.w);
    *reinterpret_cast<u16x8*>(dst + i) = o;
}

// ---------------------------------------------------------------------------
// K1: generic bf16 GEMM, m97 structure + DOUBLE-BUFFERED global_load_lds
// staging (T3-minimum: issue next tile after barrier, compute current,
// vmcnt(0)+barrier at top of iter). 128x128 tile, BK=64.
// ---------------------------------------------------------------------------
__global__ __launch_bounds__(256) void gemm_bf16(
    const unsigned short* __restrict__ A,   // bf16 [M][K]
    const unsigned short* __restrict__ B,   // bf16 [N][K]
    float* __restrict__ C,                  // fp32 [M][NC]
    int K, int NC)
{
    __shared__ alignas(16) unsigned short As[2][128 * 64];
    __shared__ alignas(16) unsigned short Bs[2][128 * 64];

    const int tid  = threadIdx.x;
    const int lane = tid & 63;
    const int w    = tid >> 6;
    const int lg   = lane >> 4, lc = lane & 15;
    const int m0   = blockIdx.y * 128, n0 = blockIdx.x * 128;

    const int rowL = lane >> 3;                 // row within 8-row chunk
    const int gS   = (lane & 7) ^ rowL;         // pre-swizzled source granule
    const int wr   = (w >> 1) * 64, wc = (w & 1) * 64;

    f32x4 acc[4][4] = {};

    auto stage = [&](int buf, int kb) {
        #pragma unroll
        for (int ci = 0; ci < 4; ci++) {
            const int chunk = w * 4 + ci;       // 0..15
            const int row   = chunk * 8 + rowL; // 0..127
            const unsigned short* gpA = &A[(size_t)(m0 + row) * K + kb + gS * 8];
            __builtin_amdgcn_global_load_lds(
                (const __attribute__((address_space(1))) void*)gpA,
                (__attribute__((address_space(3))) void*)(&As[buf][chunk * 512]),
                16, 0, 0);
            const unsigned short* gpB = &B[(size_t)(n0 + row) * K + kb + gS * 8];
            __builtin_amdgcn_global_load_lds(
                (const __attribute__((address_space(1))) void*)gpB,
                (__attribute__((address_space(3))) void*)(&Bs[buf][chunk * 512]),
                16, 0, 0);
        }
    };

    stage(0, 0);
    const int nk = K >> 6;
    for (int t = 0; t < nk; ++t) {
        asm volatile("s_waitcnt vmcnt(0)" ::: "memory");
        __syncthreads();                       // buf[t&1] staged; prev compute done
        if (t + 1 < nk) stage((t + 1) & 1, (t + 1) * 64);

        const unsigned short* As_ = As[t & 1];
        const unsigned short* Bs_ = Bs[t & 1];
        #pragma unroll
        for (int kk = 0; kk < 2; kk++) {
            u16x8 af[4], bf[4];
            #pragma unroll
            for (int mi = 0; mi < 4; mi++) {
                const int r = wr + mi * 16 + lc;
                const int g = (kk * 4 + lg) ^ (lc & 7);
                af[mi] = *reinterpret_cast<const u16x8*>(&As_[r * 64 + g * 8]);
            }
            #pragma unroll
            for (int ni = 0; ni < 4; ni++) {
                const int r = wc + ni * 16 + lc;
                const int g = (kk * 4 + lg) ^ (lc & 7);
                bf[ni] = *reinterpret_cast<const u16x8*>(&Bs_[r * 64 + g * 8]);
            }
            #pragma unroll
            for (int mi = 0; mi < 4; mi++)
                #pragma unroll
                for (int ni = 0; ni < 4; ni++)
                    acc[mi][ni] = mfma16(af[mi], bf[ni], acc[mi][ni]);
        }
        __syncthreads();                       // done reading buf[t&1]
    }

    #pragma unroll
    for (int mi = 0; mi < 4; mi++)
        #pragma unroll
        for (int ni = 0; ni < 4; ni++)
            #pragma unroll
            for (int j = 0; j < 4; j++)
                C[(size_t)(m0 + wr + mi * 16 + lg * 4 + j) * NC
                  + n0 + wc + ni * 16 + lc] = acc[mi][ni][j];
}

// ---------------------------------------------------------------------------
// K2: fp32 RoPE on q/k, emit bf16 q_rope/k_rope. One block per token.
// ---------------------------------------------------------------------------
__global__ __launch_bounds__(256) void rope_kernel(
    const float* __restrict__ qkv,
    const int* __restrict__ positions,
    unsigned short* __restrict__ qr,
    unsigned short* __restrict__ kr)
{
    const int t   = blockIdx.x;
    const int tid = threadIdx.x;
    __shared__ float cosv[64], sinv[64];

    if (tid < 64) {
        float invf = expf(-(float)tid * 0.14391156831212787f); // 10000^(-j/64)
        float f = (float)positions[t] * invf;
        cosv[tid] = cosf(f);
        sinv[tid] = sinf(f);
    }
    __syncthreads();

    const float* row = qkv + (size_t)t * QKVDIM;

    for (int i = tid; i < NH * 64; i += 256) {
        int hh = i >> 6, j = i & 63;
        float x1 = row[hh * HD + j];
        float x2 = row[hh * HD + j + 64];
        float c = cosv[j], s = sinv[j];
        qr[(size_t)t * QDIM + hh * HD + j]      = f2bf(x1 * c - x2 * s);
        qr[(size_t)t * QDIM + hh * HD + j + 64] = f2bf(x2 * c + x1 * s);
    }
    if (tid < NKV * 64) {
        int hh = tid >> 6, j = tid & 63;
        float x1 = row[QDIM + hh * HD + j];
        float x2 = row[QDIM + hh * HD + j + 64];
        float c = cosv[j], s = sinv[j];
        kr[(size_t)t * KVDIM + hh * HD + j]      = f2bf(x1 * c - x2 * s);
        kr[(size_t)t * KVDIM + hh * HD + j + 64] = f2bf(x2 * c + x1 * s);
    }
}

// ---------------------------------------------------------------------------
// K2b: V transpose: qkv fp32 V-section -> vt bf16 [KVDIM][T].
// ---------------------------------------------------------------------------
__global__ __launch_bounds__(256) void v_transpose(
    const float* __restrict__ qkv,
    unsigned short* __restrict__ vt)
{
    __shared__ unsigned short tile[64][72];
    const int tid = threadIdx.x;
    const int t0  = blockIdx.x * 64;
    const int d0  = blockIdx.y * 64;

    {
        int r = tid >> 2;
        int c = (tid & 3) * 16;
        const float* src = &qkv[(size_t)(t0 + r) * QKVDIM + QDIM + KVDIM + d0 + c];
        #pragma unroll
        for (int i = 0; i < 4; i++) {
            float4 f = *reinterpret_cast<const float4*>(src + i * 4);
            tile[r][c + i*4 + 0] = f2bf(f.x);
            tile[r][c + i*4 + 1] = f2bf(f.y);
            tile[r][c + i*4 + 2] = f2bf(f.z);
            tile[r][c + i*4 + 3] = f2bf(f.w);
        }
    }
    __syncthreads();
    {
        int dr = tid >> 3;
        int tc = (tid & 7) * 8;
        #pragma unroll
        for (int i = 0; i < 2; i++) {
            int d = dr + i * 32;
            u16x8 ov;
            #pragma unroll
            for (int e = 0; e < 8; e++) ov[e] = tile[tc + e][d];
            *reinterpret_cast<u16x8*>(&vt[(size_t)(d0 + d) * T_TOK + t0 + tc]) = ov;
        }
    }
}

// ---------------------------------------------------------------------------
// K3: causal GQA flash attention. 4-wave blocks (64 q rows, one head).
// SWAPPED QK^T (mfma(K,Q)): each lane owns one q-row's scores -> in-lane
// softmax, 2-stage shfl reduce, scalar m/ell, b64 P-writes. Defer-max
// (T13, THR=8) skips O-rescale on no-growth tiles. K/V LDS double-buffered
// (stage next tile under current compute).
// ---------------------------------------------------------------------------
__global__ __launch_bounds__(256) void attn_kernel(
    const unsigned short* __restrict__ q,   // bf16 [T][NH*HD]
    const unsigned short* __restrict__ k,   // bf16 [T][NKV*HD]
    const unsigned short* __restrict__ vt,  // bf16 [KVDIM][T] (transposed)
    unsigned short* __restrict__ o)         // bf16 [T][NH*HD]
{
    __shared__ alignas(16) unsigned short Ks[2][64 * 128];
    __shared__ alignas(16) unsigned short Vs[2][128 * 64];
    __shared__ alignas(16) unsigned short P[4][16][72];

    const int tid  = threadIdx.x;
    const int lane = tid & 63;
    const int w    = tid >> 6;
    const int lg   = lane >> 4, lc = lane & 15;
    const int b    = blockIdx.x;
    const int h    = b & 15;
    const int tile = 31 - (b >> 4);          // LPT: longest first
    const int q0   = tile * 64 + w * 16;
    const int hk   = h >> 3;
    const float scale = 0.08838834764831845f;
    const int xr   = (lc & 7) << 4;

    const int krow_l = (lane >> 4);
    const int kgS    = (lane & 15);
    const int vrow_l = (lane >> 3);
    const int vgS    = (lane & 7);

    u16x8 qf[4];
    #pragma unroll
    for (int dc = 0; dc < 4; dc++)
        qf[dc] = *reinterpret_cast<const u16x8*>(
            &q[(size_t)(q0 + lc) * QDIM + h * HD + dc * 32 + lg * 8]);

    float mrow = -1e30f, ell = 0.f;          // per-lane scalars (q-row = q0+lc)
    f32x4 oacc[8] = {};

    auto stage = [&](int buf, int kb) {
        #pragma unroll
        for (int ci = 0; ci < 4; ci++) {
            const int chunk = w * 4 + ci;
            const int row   = chunk * 4 + krow_l;
            const int gSk   = kgS ^ (row & 7);
            const unsigned short* gp =
                &k[(size_t)(kb + row) * KVDIM + hk * HD + gSk * 8];
            __builtin_amdgcn_global_load_lds(
                (const __attribute__((address_space(1))) void*)gp,
                (__attribute__((address_space(3))) void*)(&Ks[buf][chunk * 512]),
                16, 0, 0);
        }
        #pragma unroll
        for (int ci = 0; ci < 4; ci++) {
            const int chunk = w * 4 + ci;
            const int dr    = chunk * 8 + vrow_l;
            const int gSv   = vgS ^ (dr & 7);
            const unsigned short* gp =
                &vt[(size_t)(hk * HD + dr) * T_TOK + kb + gSv * 8];
            __builtin_amdgcn_global_load_lds(
                (const __attribute__((address_space(1))) void*)gp,
                (__attribute__((address_space(3))) void*)(&Vs[buf][chunk * 512]),
                16, 0, 0);
        }
    };

    const int nt = tile + 1;
    stage(0, 0);
    for (int t = 0; t < nt; ++t) {
        asm volatile("s_waitcnt vmcnt(0)" ::: "memory");
        __syncthreads();                       // buf[t&1] staged; prev reads done
        if (t + 1 < nt) stage((t + 1) & 1, (t + 1) * 64);

        const int kb = t * 64;
        const char* KsB = (const char*)Ks[t & 1];
        const char* VsB = (const char*)Vs[t & 1];

        // ---- swapped QK^T: sc[c4][j] = S[k = kb+c4*16+lg*4+j][q = q0+lc] ----
        float sc[4][4];
        #pragma unroll
        for (int c4 = 0; c4 < 4; c4++) {
            const int row = c4 * 16 + lc;      // k-position for the A-frag load
            f32x4 s = {0.f, 0.f, 0.f, 0.f};
            #pragma unroll
            for (int dc = 0; dc < 4; dc++) {
                u16x8 kf = *reinterpret_cast<const u16x8*>(
                    KsB + row * 256 + ((dc * 64 + lg * 16) ^ xr));
                s = mfma16(kf, qf[dc], s);     // SWAPPED: A=K, B=Q
            }
            #pragma unroll
            for (int j = 0; j < 4; j++) {
                const int kpos = kb + c4 * 16 + lg * 4 + j;
                const int qrow = q0 + lc;
                sc[c4][j] = (kpos <= qrow) ? s[j] * scale : -1e30f;
            }
        }

        // ---- in-lane max over this lane's 16 scores, 2-stage cross reduce ----
        float t01 = fmaxf(fmaxf(sc[0][0], sc[0][1]), fmaxf(sc[0][2], sc[0][3]));
        float t23 = fmaxf(fmaxf(sc[1][0], sc[1][1]), fmaxf(sc[1][2], sc[1][3]));
        float t45 = fmaxf(fmaxf(sc[2][0], sc[2][1]), fmaxf(sc[2][2], sc[2][3]));
        float t67 = fmaxf(fmaxf(sc[3][0], sc[3][1]), fmaxf(sc[3][2], sc[3][3]));
        float tmx = fmaxf(fmaxf(t01, t23), fmaxf(t45, t67));
        tmx = fmaxf(tmx, __shfl_xor(tmx, 16));
        tmx = fmaxf(tmx, __shfl_xor(tmx, 32));

        // ---- defer-max (T13): skip rescale when max didn't grow by >8 ----
        float mn;
        if (__all(tmx <= mrow + 8.0f)) {
            mn = mrow;
        } else {
            mn = fmaxf(mrow, tmx);
            float alpha = __expf(mrow - mn);
            mrow = mn;
            ell *= alpha;
            float aj[4];
            #pragma unroll
            for (int j = 0; j < 4; j++)
                aj[j] = __shfl(alpha, lg * 4 + j);
            #pragma unroll
            for (int d8 = 0; d8 < 8; d8++)
                #pragma unroll
                for (int j = 0; j < 4; j++)
                    oacc[d8][j] *= aj[j];
        }

        // ---- exp + row-sum + packed P write (b64 per c4) ----
        float rs = 0.f;
        #pragma unroll
        for (int c4 = 0; c4 < 4; c4++) {
            float p0 = __expf(sc[c4][0] - mn);
            float p1 = __expf(sc[c4][1] - mn);
            float p2 = __expf(sc[c4][2] - mn);
            float p3 = __expf(sc[c4][3] - mn);
            rs += (p0 + p1) + (p2 + p3);
            ushort4 pk;
            pk.x = f2bf(p0); pk.y = f2bf(p1); pk.z = f2bf(p2); pk.w = f2bf(p3);
            *reinterpret_cast<ushort4*>(&P[w][lc][c4 * 16 + lg * 4]) = pk;
        }
        rs += __shfl_xor(rs, 16);
        rs += __shfl_xor(rs, 32);
        ell += rs;

        // per-wave LDS write->read: drain LDS queue, pin schedule (rule #18)
        asm volatile("s_waitcnt lgkmcnt(0)" ::: "memory");
        __builtin_amdgcn_sched_barrier(0);

        u16x8 pf0 = *reinterpret_cast<const u16x8*>(&P[w][lc][lg * 8]);
        u16x8 pf1 = *reinterpret_cast<const u16x8*>(&P[w][lc][32 + lg * 8]);

        // ---- PV ----
        #pragma unroll
        for (int d8 = 0; d8 < 8; d8++) {
            const int drow = d8 * 16 + lc;
            u16x8 vf0 = *reinterpret_cast<const u16x8*>(
                VsB + drow * 128 + ((lg * 16) ^ xr));
            u16x8 vf1 = *reinterpret_cast<const u16x8*>(
                VsB + drow * 128 + ((lg * 16 + 64) ^ xr));
            oacc[d8] = mfma16(pf0, vf0, oacc[d8]);
            oacc[d8] = mfma16(pf1, vf1, oacc[d8]);
        }
        __syncthreads();                       // done reading buf[t&1]
    }

    float ej[4];
    #pragma unroll
    for (int j = 0; j < 4; j++)
        ej[j] = __shfl(ell, lg * 4 + j);
    #pragma unroll
    for (int d8 = 0; d8 < 8; d8++)
        #pragma unroll
        for (int j = 0; j < 4; j++) {
            float val = oacc[d8][j] / ej[j];
            o[(size_t)(q0 + lg * 4 + j) * QDIM + h * HD + d8 * 16 + lc] = f2bf(val);
        }
}

// ---------------------------------------------------------------------------
extern "C" void kernel_launch(void* const* d_in, const int* in_sizes, int n_in,
                              void* d_out, int out_size, void* d_ws, size_t ws_size,
                              hipStream_t stream) {
    const float* hidden    = (const float*)d_in[0];
    const int*   positions = (const int*)d_in[1];
    const float* Wq        = (const float*)d_in[2];
    const float* Wk        = (const float*)d_in[3];
    const float* Wv        = (const float*)d_in[4];
    const float* Wo        = (const float*)d_in[5];
    float*       out       = (float*)d_out;

    char* ws = (char*)d_ws;
    float*          qkv = (float*)(ws);                     // 20971520 B
    unsigned short* qr  = (unsigned short*)(ws + 20971520); // 8388608 B
    unsigned short* kr  = (unsigned short*)(ws + 29360128); // 1048576 B
    unsigned short* vt  = (unsigned short*)(ws + 30408704); // 1048576 B
    unsigned short* att = (unsigned short*)(ws + 31457280); // 8388608 B
    unsigned short* hb  = (unsigned short*)(ws + 39845888); // 8388608 B  bf16 hidden
    unsigned short* Wf  = (unsigned short*)(ws + 48234496); // 10485760 B bf16 [Wq;Wk;Wv]
    unsigned short* Wob = (unsigned short*)(ws + 58720256); // 8388608 B  bf16 Wo
    // total 67108864 B = 64 MB

    pack_bf16_all<<<6656, 256, 0, stream>>>(hidden, Wq, Wk, Wv, Wo, hb, Wf, Wob);
    gemm_bf16<<<dim3(QKVDIM / 128, T_TOK / 128), 256, 0, stream>>>(hb, Wf, qkv, HID, QKVDIM);
    rope_kernel<<<T_TOK, 256, 0, stream>>>(qkv, positions, qr, kr);
    v_transpose<<<dim3(T_TOK / 64, KVDIM / 64), 256, 0, stream>>>(qkv, vt);
    attn_kernel<<<NH * (T_TOK / 64), 256, 0, stream>>>(qr, kr, vt, att);
    gemm_bf16<<<dim3(HID / 128, T_TOK / 128), 256, 0, stream>>>(att, Wob, out, QDIM, HID);
}

// Round 7
// 147.832 us; speedup vs baseline: 2.6803x; 1.0816x over previous
//
#include <hip/hip_runtime.h>

#define T_TOK 2048
#define HID   2048
#define NH    16
#define NKV   2
#define HD    128
#define QDIM  (NH * HD)                 // 2048
#define KVDIM (NKV * HD)                // 256
#define QKVDIM (QDIM + 2 * KVDIM)       // 2560

typedef float          f32x4  __attribute__((ext_vector_type(4)));
typedef unsigned short u16x8  __attribute__((ext_vector_type(8)));
typedef __bf16         bf16x8 __attribute__((ext_vector_type(8)));

__device__ __forceinline__ unsigned short f2bf(float f) {
    unsigned int u = __builtin_bit_cast(unsigned int, f);
    u += 0x7fffu + ((u >> 16) & 1u);   // round-to-nearest-even
    return (unsigned short)(u >> 16);
}

__device__ __forceinline__ f32x4 mfma16(u16x8 a, u16x8 b, f32x4 c) {
    return __builtin_amdgcn_mfma_f32_16x16x32_bf16(
        __builtin_bit_cast(bf16x8, a), __builtin_bit_cast(bf16x8, b), c, 0, 0, 0);
}

// ---------------------------------------------------------------------------
// K0: convert all fp32 operands to bf16 once (memory-bound pass).
// ---------------------------------------------------------------------------
__global__ __launch_bounds__(256) void pack_bf16_all(
    const float* __restrict__ hidden, const float* __restrict__ Wq,
    const float* __restrict__ Wk, const float* __restrict__ Wv,
    const float* __restrict__ Wo,
    unsigned short* __restrict__ hb, unsigned short* __restrict__ Wf,
    unsigned short* __restrict__ Wob)
{
    const int b = blockIdx.x;
    const float* src; unsigned short* dst; size_t off;
    if      (b < 2048) { src = hidden; dst = hb;            off = (size_t)b * 2048; }
    else if (b < 4096) { src = Wq;     dst = Wf;            off = (size_t)(b - 2048) * 2048; }
    else if (b < 4352) { src = Wk;     dst = Wf + 4194304;  off = (size_t)(b - 4096) * 2048; }
    else if (b < 4608) { src = Wv;     dst = Wf + 4718592;  off = (size_t)(b - 4352) * 2048; }
    else               { src = Wo;     dst = Wob;           off = (size_t)(b - 4608) * 2048; }

    const size_t i = off + threadIdx.x * 8;
    float4 f0 = *reinterpret_cast<const float4*>(src + i);
    float4 f1 = *reinterpret_cast<const float4*>(src + i + 4);
    u16x8 o;
    o[0]=f2bf(f0.x); o[1]=f2bf(f0.y); o[2]=f2bf(f0.z); o[3]=f2bf(f0.w);
    o[4]=f2bf(f1.x); o[5]=f2bf(f1.y); o[6]=f2bf(f1.z); o[7]=f2bf(f1.w);
    *reinterpret_cast<u16x8*>(dst + i) = o;
}

// ---------------------------------------------------------------------------
// K1: generic bf16 GEMM, m97 structure + double-buffered global_load_lds.
// ---------------------------------------------------------------------------
__global__ __launch_bounds__(256) void gemm_bf16(
    const unsigned short* __restrict__ A,   // bf16 [M][K]
    const unsigned short* __restrict__ B,   // bf16 [N][K]
    float* __restrict__ C,                  // fp32 [M][NC]
    int K, int NC)
{
    __shared__ alignas(16) unsigned short As[2][128 * 64];
    __shared__ alignas(16) unsigned short Bs[2][128 * 64];

    const int tid  = threadIdx.x;
    const int lane = tid & 63;
    const int w    = tid >> 6;
    const int lg   = lane >> 4, lc = lane & 15;
    const int m0   = blockIdx.y * 128, n0 = blockIdx.x * 128;

    const int rowL = lane >> 3;
    const int gS   = (lane & 7) ^ rowL;
    const int wr   = (w >> 1) * 64, wc = (w & 1) * 64;

    f32x4 acc[4][4] = {};

    auto stage = [&](int buf, int kb) {
        #pragma unroll
        for (int ci = 0; ci < 4; ci++) {
            const int chunk = w * 4 + ci;
            const int row   = chunk * 8 + rowL;
            const unsigned short* gpA = &A[(size_t)(m0 + row) * K + kb + gS * 8];
            __builtin_amdgcn_global_load_lds(
                (const __attribute__((address_space(1))) void*)gpA,
                (__attribute__((address_space(3))) void*)(&As[buf][chunk * 512]),
                16, 0, 0);
            const unsigned short* gpB = &B[(size_t)(n0 + row) * K + kb + gS * 8];
            __builtin_amdgcn_global_load_lds(
                (const __attribute__((address_space(1))) void*)gpB,
                (__attribute__((address_space(3))) void*)(&Bs[buf][chunk * 512]),
                16, 0, 0);
        }
    };

    stage(0, 0);
    const int nk = K >> 6;
    for (int t = 0; t < nk; ++t) {
        asm volatile("s_waitcnt vmcnt(0)" ::: "memory");
        __syncthreads();
        if (t + 1 < nk) stage((t + 1) & 1, (t + 1) * 64);

        const unsigned short* As_ = As[t & 1];
        const unsigned short* Bs_ = Bs[t & 1];
        #pragma unroll
        for (int kk = 0; kk < 2; kk++) {
            u16x8 af[4], bf[4];
            #pragma unroll
            for (int mi = 0; mi < 4; mi++) {
                const int r = wr + mi * 16 + lc;
                const int g = (kk * 4 + lg) ^ (lc & 7);
                af[mi] = *reinterpret_cast<const u16x8*>(&As_[r * 64 + g * 8]);
            }
            #pragma unroll
            for (int ni = 0; ni < 4; ni++) {
                const int r = wc + ni * 16 + lc;
                const int g = (kk * 4 + lg) ^ (lc & 7);
                bf[ni] = *reinterpret_cast<const u16x8*>(&Bs_[r * 64 + g * 8]);
            }
            #pragma unroll
            for (int mi = 0; mi < 4; mi++)
                #pragma unroll
                for (int ni = 0; ni < 4; ni++)
                    acc[mi][ni] = mfma16(af[mi], bf[ni], acc[mi][ni]);
        }
        __syncthreads();
    }

    #pragma unroll
    for (int mi = 0; mi < 4; mi++)
        #pragma unroll
        for (int ni = 0; ni < 4; ni++)
            #pragma unroll
            for (int j = 0; j < 4; j++)
                C[(size_t)(m0 + wr + mi * 16 + lg * 4 + j) * NC
                  + n0 + wc + ni * 16 + lc] = acc[mi][ni][j];
}

// ---------------------------------------------------------------------------
// K2: fp32 RoPE on q/k, emit bf16 q_rope/k_rope. One block per token.
// ---------------------------------------------------------------------------
__global__ __launch_bounds__(256) void rope_kernel(
    const float* __restrict__ qkv,
    const int* __restrict__ positions,
    unsigned short* __restrict__ qr,
    unsigned short* __restrict__ kr)
{
    const int t   = blockIdx.x;
    const int tid = threadIdx.x;
    __shared__ float cosv[64], sinv[64];

    if (tid < 64) {
        float invf = expf(-(float)tid * 0.14391156831212787f); // 10000^(-j/64)
        float f = (float)positions[t] * invf;
        cosv[tid] = cosf(f);
        sinv[tid] = sinf(f);
    }
    __syncthreads();

    const float* row = qkv + (size_t)t * QKVDIM;

    for (int i = tid; i < NH * 64; i += 256) {
        int hh = i >> 6, j = i & 63;
        float x1 = row[hh * HD + j];
        float x2 = row[hh * HD + j + 64];
        float c = cosv[j], s = sinv[j];
        qr[(size_t)t * QDIM + hh * HD + j]      = f2bf(x1 * c - x2 * s);
        qr[(size_t)t * QDIM + hh * HD + j + 64] = f2bf(x2 * c + x1 * s);
    }
    if (tid < NKV * 64) {
        int hh = tid >> 6, j = tid & 63;
        float x1 = row[QDIM + hh * HD + j];
        float x2 = row[QDIM + hh * HD + j + 64];
        float c = cosv[j], s = sinv[j];
        kr[(size_t)t * KVDIM + hh * HD + j]      = f2bf(x1 * c - x2 * s);
        kr[(size_t)t * KVDIM + hh * HD + j + 64] = f2bf(x2 * c + x1 * s);
    }
}

// ---------------------------------------------------------------------------
// K2b: V transpose: qkv fp32 V-section -> vt bf16 [KVDIM][T].
// ---------------------------------------------------------------------------
__global__ __launch_bounds__(256) void v_transpose(
    const float* __restrict__ qkv,
    unsigned short* __restrict__ vt)
{
    __shared__ unsigned short tile[64][72];
    const int tid = threadIdx.x;
    const int t0  = blockIdx.x * 64;
    const int d0  = blockIdx.y * 64;

    {
        int r = tid >> 2;
        int c = (tid & 3) * 16;
        const float* src = &qkv[(size_t)(t0 + r) * QKVDIM + QDIM + KVDIM + d0 + c];
        #pragma unroll
        for (int i = 0; i < 4; i++) {
            float4 f = *reinterpret_cast<const float4*>(src + i * 4);
            tile[r][c + i*4 + 0] = f2bf(f.x);
            tile[r][c + i*4 + 1] = f2bf(f.y);
            tile[r][c + i*4 + 2] = f2bf(f.z);
            tile[r][c + i*4 + 3] = f2bf(f.w);
        }
    }
    __syncthreads();
    {
        int dr = tid >> 3;
        int tc = (tid & 7) * 8;
        #pragma unroll
        for (int i = 0; i < 2; i++) {
            int d = dr + i * 32;
            u16x8 ov;
            #pragma unroll
            for (int e = 0; e < 8; e++) ov[e] = tile[tc + e][d];
            *reinterpret_cast<u16x8*>(&vt[(size_t)(d0 + d) * T_TOK + t0 + tc]) = ov;
        }
    }
}

// ---------------------------------------------------------------------------
// K3: causal GQA flash attention with SPLIT-K over the key dimension.
// Block = (head, q-tile-of-64, k-chunk of <=16 k-blocks). Tiles 0..15:
// single chunk, direct normalized write. Tiles 16..31: 2 chunks, fp32
// partial (O,m,ell) + combine pass. LPT: 16-iter chunks dispatched first.
// Grid = 16 heads * 48 entries = 768 blocks (512 resident, 256 refill).
// ---------------------------------------------------------------------------
__global__ __launch_bounds__(256) void attn_kernel(
    const unsigned short* __restrict__ q,   // bf16 [T][NH*HD]
    const unsigned short* __restrict__ k,   // bf16 [T][NKV*HD]
    const unsigned short* __restrict__ vt,  // bf16 [KVDIM][T] (transposed)
    unsigned short* __restrict__ o,         // bf16 [T][NH*HD]
    float* __restrict__ pO,                 // fp32 [512][64][128] partials
    float* __restrict__ pML)                // fp32 [512][2][64]  (m, ell)
{
    __shared__ alignas(16) unsigned short Ks[2][64 * 128];
    __shared__ alignas(16) unsigned short Vs[2][128 * 64];
    __shared__ alignas(16) unsigned short P[4][16][72];

    const int tid  = threadIdx.x;
    const int lane = tid & 63;
    const int w    = tid >> 6;
    const int lg   = lane >> 4, lc = lane & 15;
    const int b    = blockIdx.x;
    const int h    = b & 15;
    const int idx  = b >> 4;                 // 0..47, descending work (LPT)

    // idx -> (tau, chunk): 0..16 -> (15+idx, 0); 17 -> (31,1);
    // 18.. -> pairs (k-1,0)/(k+15,1) for k=15..1
    int tau, c0;
    if (idx <= 16)      { tau = 15 + idx; c0 = 0; }
    else if (idx == 17) { tau = 31;       c0 = 1; }
    else {
        int j = idx - 18, kk = 15 - (j >> 1);
        if ((j & 1) == 0) { tau = kk - 1;  c0 = 0; }
        else              { tau = kk + 15; c0 = 1; }
    }
    const int kstart = c0 << 4;                       // in 64-key blocks
    const int kcnt   = min(16, tau + 1 - kstart);

    const int q0   = tau * 64 + w * 16;
    const int hk   = h >> 3;
    const float scale = 0.08838834764831845f;
    const int xr   = (lc & 7) << 4;

    const int krow_l = (lane >> 4);
    const int kgS    = (lane & 15);
    const int vrow_l = (lane >> 3);
    const int vgS    = (lane & 7);

    u16x8 qf[4];
    #pragma unroll
    for (int dc = 0; dc < 4; dc++)
        qf[dc] = *reinterpret_cast<const u16x8*>(
            &q[(size_t)(q0 + lc) * QDIM + h * HD + dc * 32 + lg * 8]);

    float mrow = -1e30f, ell = 0.f;
    f32x4 oacc[8] = {};

    auto stage = [&](int buf, int kb) {
        #pragma unroll
        for (int ci = 0; ci < 4; ci++) {
            const int chunk = w * 4 + ci;
            const int row   = chunk * 4 + krow_l;
            const int gSk   = kgS ^ (row & 7);
            const unsigned short* gp =
                &k[(size_t)(kb + row) * KVDIM + hk * HD + gSk * 8];
            __builtin_amdgcn_global_load_lds(
                (const __attribute__((address_space(1))) void*)gp,
                (__attribute__((address_space(3))) void*)(&Ks[buf][chunk * 512]),
                16, 0, 0);
        }
        #pragma unroll
        for (int ci = 0; ci < 4; ci++) {
            const int chunk = w * 4 + ci;
            const int dr    = chunk * 8 + vrow_l;
            const int gSv   = vgS ^ (dr & 7);
            const unsigned short* gp =
                &vt[(size_t)(hk * HD + dr) * T_TOK + kb + gSv * 8];
            __builtin_amdgcn_global_load_lds(
                (const __attribute__((address_space(1))) void*)gp,
                (__attribute__((address_space(3))) void*)(&Vs[buf][chunk * 512]),
                16, 0, 0);
        }
    };

    stage(0, kstart * 64);
    for (int it = 0; it < kcnt; ++it) {
        asm volatile("s_waitcnt vmcnt(0)" ::: "memory");
        __syncthreads();
        if (it + 1 < kcnt) stage((it + 1) & 1, (kstart + it + 1) * 64);

        const int kb = (kstart + it) * 64;
        const char* KsB = (const char*)Ks[it & 1];
        const char* VsB = (const char*)Vs[it & 1];

        // swapped QK^T: lane owns q-row q0+lc, 16 k-scores
        float sc[4][4];
        #pragma unroll
        for (int c4 = 0; c4 < 4; c4++) {
            const int row = c4 * 16 + lc;
            f32x4 s = {0.f, 0.f, 0.f, 0.f};
            #pragma unroll
            for (int dc = 0; dc < 4; dc++) {
                u16x8 kf = *reinterpret_cast<const u16x8*>(
                    KsB + row * 256 + ((dc * 64 + lg * 16) ^ xr));
                s = mfma16(kf, qf[dc], s);     // SWAPPED: A=K, B=Q
            }
            #pragma unroll
            for (int j = 0; j < 4; j++) {
                const int kpos = kb + c4 * 16 + lg * 4 + j;
                const int qrow = q0 + lc;
                sc[c4][j] = (kpos <= qrow) ? s[j] * scale : -1e30f;
            }
        }

        float t01 = fmaxf(fmaxf(sc[0][0], sc[0][1]), fmaxf(sc[0][2], sc[0][3]));
        float t23 = fmaxf(fmaxf(sc[1][0], sc[1][1]), fmaxf(sc[1][2], sc[1][3]));
        float t45 = fmaxf(fmaxf(sc[2][0], sc[2][1]), fmaxf(sc[2][2], sc[2][3]));
        float t67 = fmaxf(fmaxf(sc[3][0], sc[3][1]), fmaxf(sc[3][2], sc[3][3]));
        float tmx = fmaxf(fmaxf(t01, t23), fmaxf(t45, t67));
        tmx = fmaxf(tmx, __shfl_xor(tmx, 16));
        tmx = fmaxf(tmx, __shfl_xor(tmx, 32));

        float mn;
        if (__all(tmx <= mrow + 8.0f)) {       // defer-max (T13)
            mn = mrow;
        } else {
            mn = fmaxf(mrow, tmx);
            float alpha = __expf(mrow - mn);
            mrow = mn;
            ell *= alpha;
            float aj[4];
            #pragma unroll
            for (int j = 0; j < 4; j++)
                aj[j] = __shfl(alpha, lg * 4 + j);
            #pragma unroll
            for (int d8 = 0; d8 < 8; d8++)
                #pragma unroll
                for (int j = 0; j < 4; j++)
                    oacc[d8][j] *= aj[j];
        }

        float rs = 0.f;
        #pragma unroll
        for (int c4 = 0; c4 < 4; c4++) {
            float p0 = __expf(sc[c4][0] - mn);
            float p1 = __expf(sc[c4][1] - mn);
            float p2 = __expf(sc[c4][2] - mn);
            float p3 = __expf(sc[c4][3] - mn);
            rs += (p0 + p1) + (p2 + p3);
            ushort4 pk;
            pk.x = f2bf(p0); pk.y = f2bf(p1); pk.z = f2bf(p2); pk.w = f2bf(p3);
            *reinterpret_cast<ushort4*>(&P[w][lc][c4 * 16 + lg * 4]) = pk;
        }
        rs += __shfl_xor(rs, 16);
        rs += __shfl_xor(rs, 32);
        ell += rs;

        asm volatile("s_waitcnt lgkmcnt(0)" ::: "memory");
        __builtin_amdgcn_sched_barrier(0);

        u16x8 pf0 = *reinterpret_cast<const u16x8*>(&P[w][lc][lg * 8]);
        u16x8 pf1 = *reinterpret_cast<const u16x8*>(&P[w][lc][32 + lg * 8]);

        #pragma unroll
        for (int d8 = 0; d8 < 8; d8++) {
            const int drow = d8 * 16 + lc;
            u16x8 vf0 = *reinterpret_cast<const u16x8*>(
                VsB + drow * 128 + ((lg * 16) ^ xr));
            u16x8 vf1 = *reinterpret_cast<const u16x8*>(
                VsB + drow * 128 + ((lg * 16 + 64) ^ xr));
            oacc[d8] = mfma16(pf0, vf0, oacc[d8]);
            oacc[d8] = mfma16(pf1, vf1, oacc[d8]);
        }
        __syncthreads();
    }

    if (tau < 16) {
        // single chunk: normalized direct write
        float ej[4];
        #pragma unroll
        for (int j = 0; j < 4; j++)
            ej[j] = __shfl(ell, lg * 4 + j);
        #pragma unroll
        for (int d8 = 0; d8 < 8; d8++)
            #pragma unroll
            for (int j = 0; j < 4; j++) {
                float val = oacc[d8][j] / ej[j];
                o[(size_t)(q0 + lg * 4 + j) * QDIM + h * HD + d8 * 16 + lc] = f2bf(val);
            }
    } else {
        // partial write (fp32 O, m, ell)
        const int s = (h * 16 + (tau - 16)) * 2 + c0;
        float* po = pO + (size_t)s * 8192;
        #pragma unroll
        for (int d8 = 0; d8 < 8; d8++)
            #pragma unroll
            for (int j = 0; j < 4; j++)
                po[(w * 16 + lg * 4 + j) * 128 + d8 * 16 + lc] = oacc[d8][j];
        if (lg == 0) {
            pML[s * 128 + w * 16 + lc]      = mrow;
            pML[s * 128 + 64 + w * 16 + lc] = ell;
        }
    }
}

// ---------------------------------------------------------------------------
// K3b: combine two split-K partials -> normalized bf16 output.
// Grid 256 = 16 heads x 16 tiles (tau = 16+ti). 256 threads.
// ---------------------------------------------------------------------------
__global__ __launch_bounds__(256) void attn_combine(
    const float* __restrict__ pO,
    const float* __restrict__ pML,
    unsigned short* __restrict__ o)
{
    const int b  = blockIdx.x;
    const int h  = b >> 4, ti = b & 15;
    const int tau = 16 + ti;
    const int s0 = (h * 16 + ti) * 2, s1 = s0 + 1;

    const int tid = threadIdx.x;
    const int r   = tid >> 2;             // 0..63
    const int cg  = (tid & 3) * 32;       // 0,32,64,96

    const float m1 = pML[s0 * 128 + r],      m2 = pML[s1 * 128 + r];
    const float l1 = pML[s0 * 128 + 64 + r], l2 = pML[s1 * 128 + 64 + r];
    const float M  = fmaxf(m1, m2);
    const float w1 = __expf(m1 - M), w2 = __expf(m2 - M);
    const float rn = 1.0f / (w1 * l1 + w2 * l2);

    const float* o1 = pO + (size_t)s0 * 8192 + r * 128 + cg;
    const float* o2 = pO + (size_t)s1 * 8192 + r * 128 + cg;
    unsigned short* dst = o + (size_t)(tau * 64 + r) * QDIM + h * HD + cg;

    #pragma unroll
    for (int i = 0; i < 8; i++) {
        float4 a = *reinterpret_cast<const float4*>(o1 + i * 4);
        float4 c = *reinterpret_cast<const float4*>(o2 + i * 4);
        ushort4 pk;
        pk.x = f2bf((w1 * a.x + w2 * c.x) * rn);
        pk.y = f2bf((w1 * a.y + w2 * c.y) * rn);
        pk.z = f2bf((w1 * a.z + w2 * c.z) * rn);
        pk.w = f2bf((w1 * a.w + w2 * c.w) * rn);
        *reinterpret_cast<ushort4*>(dst + i * 4) = pk;
    }
}

// ---------------------------------------------------------------------------
extern "C" void kernel_launch(void* const* d_in, const int* in_sizes, int n_in,
                              void* d_out, int out_size, void* d_ws, size_t ws_size,
                              hipStream_t stream) {
    const float* hidden    = (const float*)d_in[0];
    const int*   positions = (const int*)d_in[1];
    const float* Wq        = (const float*)d_in[2];
    const float* Wk        = (const float*)d_in[3];
    const float* Wv        = (const float*)d_in[4];
    const float* Wo        = (const float*)d_in[5];
    float*       out       = (float*)d_out;

    char* ws = (char*)d_ws;
    float*          qkv = (float*)(ws);                     // [0, 20971520)
    unsigned short* qr  = (unsigned short*)(ws + 20971520); // 8388608 B
    unsigned short* kr  = (unsigned short*)(ws + 29360128); // 1048576 B
    unsigned short* vt  = (unsigned short*)(ws + 30408704); // 1048576 B
    unsigned short* att = (unsigned short*)(ws + 31457280); // 8388608 B
    unsigned short* hb  = (unsigned short*)(ws + 39845888); // 8388608 B
    unsigned short* Wf  = (unsigned short*)(ws + 48234496); // 10485760 B
    unsigned short* Wob = (unsigned short*)(ws + 58720256); // 8388608 B
    // split-K partials ALIAS the qkv region (qkv dead once v_transpose ran):
    float* pO  = (float*)(ws);              // 512*8192*4 = 16777216 B
    float* pML = (float*)(ws + 16777216);   // 512*128*4  =   262144 B  (< 20971520)

    pack_bf16_all<<<6656, 256, 0, stream>>>(hidden, Wq, Wk, Wv, Wo, hb, Wf, Wob);
    gemm_bf16<<<dim3(QKVDIM / 128, T_TOK / 128), 256, 0, stream>>>(hb, Wf, qkv, HID, QKVDIM);
    rope_kernel<<<T_TOK, 256, 0, stream>>>(qkv, positions, qr, kr);
    v_transpose<<<dim3(T_TOK / 64, KVDIM / 64), 256, 0, stream>>>(qkv, vt);
    attn_kernel<<<NH * 48, 256, 0, stream>>>(qr, kr, vt, att, pO, pML);
    attn_combine<<<256, 256, 0, stream>>>(pO, pML, att);
    gemm_bf16<<<dim3(HID / 128, T_TOK / 128), 256, 0, stream>>>(att, Wob, out, QDIM, HID);
}

// Round 8
// 145.631 us; speedup vs baseline: 2.7208x; 1.0151x over previous
//
#include <hip/hip_runtime.h>

#define T_TOK 2048
#define HID   2048
#define NH    16
#define NKV   2
#define HD    128
#define QDIM  (NH * HD)                 // 2048
#define KVDIM (NKV * HD)                // 256
#define QKVDIM (QDIM + 2 * KVDIM)       // 2560

typedef float          f32x4  __attribute__((ext_vector_type(4)));
typedef unsigned short u16x8  __attribute__((ext_vector_type(8)));
typedef __bf16         bf16x8 __attribute__((ext_vector_type(8)));

__device__ __forceinline__ unsigned short f2bf(float f) {
    __bf16 h = (__bf16)f;                      // HW RNE convert (v_cvt_pk_bf16_f32)
    return __builtin_bit_cast(unsigned short, h);
}
__device__ __forceinline__ float bf2f(unsigned short u) {
    return (float)__builtin_bit_cast(__bf16, u);
}

__device__ __forceinline__ f32x4 mfma16(u16x8 a, u16x8 b, f32x4 c) {
    return __builtin_amdgcn_mfma_f32_16x16x32_bf16(
        __builtin_bit_cast(bf16x8, a), __builtin_bit_cast(bf16x8, b), c, 0, 0, 0);
}

// scale * log2(e): Q pre-scaled so QK^T scores are directly in log2 units
#define QSCL 0.12751743f
// defer-max threshold 8 (nat) -> log2 units
#define DEFER_THR 11.5416f

// ---------------------------------------------------------------------------
// K0: convert all fp32 operands to bf16 once (memory-bound pass).
// ---------------------------------------------------------------------------
__global__ __launch_bounds__(256) void pack_bf16_all(
    const float* __restrict__ hidden, const float* __restrict__ Wq,
    const float* __restrict__ Wk, const float* __restrict__ Wv,
    const float* __restrict__ Wo,
    unsigned short* __restrict__ hb, unsigned short* __restrict__ Wf,
    unsigned short* __restrict__ Wob)
{
    const int b = blockIdx.x;
    const float* src; unsigned short* dst; size_t off;
    if      (b < 2048) { src = hidden; dst = hb;            off = (size_t)b * 2048; }
    else if (b < 4096) { src = Wq;     dst = Wf;            off = (size_t)(b - 2048) * 2048; }
    else if (b < 4352) { src = Wk;     dst = Wf + 4194304;  off = (size_t)(b - 4096) * 2048; }
    else if (b < 4608) { src = Wv;     dst = Wf + 4718592;  off = (size_t)(b - 4352) * 2048; }
    else               { src = Wo;     dst = Wob;           off = (size_t)(b - 4608) * 2048; }

    const size_t i = off + threadIdx.x * 8;
    float4 f0 = *reinterpret_cast<const float4*>(src + i);
    float4 f1 = *reinterpret_cast<const float4*>(src + i + 4);
    u16x8 o;
    o[0]=f2bf(f0.x); o[1]=f2bf(f0.y); o[2]=f2bf(f0.z); o[3]=f2bf(f0.w);
    o[4]=f2bf(f1.x); o[5]=f2bf(f1.y); o[6]=f2bf(f1.z); o[7]=f2bf(f1.w);
    *reinterpret_cast<u16x8*>(dst + i) = o;
}

// ---------------------------------------------------------------------------
// K1: generic bf16 GEMM, 128x128 / BK=64, double-buffered global_load_lds
// with COUNTED vmcnt(8) (T4: next tile's loads stay in flight across the
// barrier). Bijective XCD swizzle on a flat grid (T1; nwg % 8 == 0).
// ---------------------------------------------------------------------------
template<bool BF16OUT>
__global__ __launch_bounds__(256) void gemm_bf16(
    const unsigned short* __restrict__ A,   // bf16 [M][K]
    const unsigned short* __restrict__ B,   // bf16 [N][K]
    void* __restrict__ Cv,                  // fp32 or bf16 [M][NC]
    int K, int NC, int nbx)
{
    __shared__ alignas(16) unsigned short As[2][128 * 64];
    __shared__ alignas(16) unsigned short Bs[2][128 * 64];

    const int tid  = threadIdx.x;
    const int lane = tid & 63;
    const int w    = tid >> 6;
    const int lg   = lane >> 4, lc = lane & 15;

    // XCD-aware bijective remap (nwg % 8 == 0)
    const int cpx = gridDim.x >> 3;
    const int wg  = (blockIdx.x & 7) * cpx + (blockIdx.x >> 3);
    const int m0  = (wg / nbx) * 128, n0 = (wg % nbx) * 128;

    const int rowL = lane >> 3;
    const int gS   = (lane & 7) ^ rowL;
    const int wr   = (w >> 1) * 64, wc = (w & 1) * 64;

    f32x4 acc[4][4] = {};

    auto stage = [&](int buf, int kb) {
        #pragma unroll
        for (int ci = 0; ci < 4; ci++) {
            const int chunk = w * 4 + ci;
            const int row   = chunk * 8 + rowL;
            const unsigned short* gpA = &A[(size_t)(m0 + row) * K + kb + gS * 8];
            __builtin_amdgcn_global_load_lds(
                (const __attribute__((address_space(1))) void*)gpA,
                (__attribute__((address_space(3))) void*)(&As[buf][chunk * 512]),
                16, 0, 0);
            const unsigned short* gpB = &B[(size_t)(n0 + row) * K + kb + gS * 8];
            __builtin_amdgcn_global_load_lds(
                (const __attribute__((address_space(1))) void*)gpB,
                (__attribute__((address_space(3))) void*)(&Bs[buf][chunk * 512]),
                16, 0, 0);
        }
    };

    stage(0, 0);
    const int nk = K >> 6;
    for (int t = 0; t < nk; ++t) {
        if (t + 1 < nk) {
            stage((t + 1) & 1, (t + 1) * 64);   // issue BEFORE wait
            asm volatile("s_waitcnt vmcnt(8)" ::: "memory");  // stage(t) done
        } else {
            asm volatile("s_waitcnt vmcnt(0)" ::: "memory");
        }
        __syncthreads();

        const unsigned short* As_ = As[t & 1];
        const unsigned short* Bs_ = Bs[t & 1];
        #pragma unroll
        for (int kk = 0; kk < 2; kk++) {
            u16x8 af[4], bf[4];
            #pragma unroll
            for (int mi = 0; mi < 4; mi++) {
                const int r = wr + mi * 16 + lc;
                const int g = (kk * 4 + lg) ^ (lc & 7);
                af[mi] = *reinterpret_cast<const u16x8*>(&As_[r * 64 + g * 8]);
            }
            #pragma unroll
            for (int ni = 0; ni < 4; ni++) {
                const int r = wc + ni * 16 + lc;
                const int g = (kk * 4 + lg) ^ (lc & 7);
                bf[ni] = *reinterpret_cast<const u16x8*>(&Bs_[r * 64 + g * 8]);
            }
            #pragma unroll
            for (int mi = 0; mi < 4; mi++)
                #pragma unroll
                for (int ni = 0; ni < 4; ni++)
                    acc[mi][ni] = mfma16(af[mi], bf[ni], acc[mi][ni]);
        }
        __syncthreads();
    }

    #pragma unroll
    for (int mi = 0; mi < 4; mi++)
        #pragma unroll
        for (int ni = 0; ni < 4; ni++)
            #pragma unroll
            for (int j = 0; j < 4; j++) {
                const size_t idx = (size_t)(m0 + wr + mi * 16 + lg * 4 + j) * NC
                                   + n0 + wc + ni * 16 + lc;
                if constexpr (BF16OUT)
                    ((unsigned short*)Cv)[idx] = f2bf(acc[mi][ni][j]);
                else
                    ((float*)Cv)[idx] = acc[mi][ni][j];
            }
}

// ---------------------------------------------------------------------------
// K2: RoPE on bf16 qkv -> bf16 q_rope (PRE-SCALED by scale*log2e) / k_rope.
// ---------------------------------------------------------------------------
__global__ __launch_bounds__(256) void rope_kernel(
    const unsigned short* __restrict__ qkvb,
    const int* __restrict__ positions,
    unsigned short* __restrict__ qr,
    unsigned short* __restrict__ kr)
{
    const int t   = blockIdx.x;
    const int tid = threadIdx.x;
    __shared__ float cosv[64], sinv[64];

    if (tid < 64) {
        float invf = expf(-(float)tid * 0.14391156831212787f); // 10000^(-j/64)
        float f = (float)positions[t] * invf;
        cosv[tid] = cosf(f);
        sinv[tid] = sinf(f);
    }
    __syncthreads();

    const unsigned short* row = qkvb + (size_t)t * QKVDIM;

    for (int i = tid; i < NH * 64; i += 256) {
        int hh = i >> 6, j = i & 63;
        float x1 = bf2f(row[hh * HD + j]);
        float x2 = bf2f(row[hh * HD + j + 64]);
        float c = cosv[j], s = sinv[j];
        qr[(size_t)t * QDIM + hh * HD + j]      = f2bf((x1 * c - x2 * s) * QSCL);
        qr[(size_t)t * QDIM + hh * HD + j + 64] = f2bf((x2 * c + x1 * s) * QSCL);
    }
    if (tid < NKV * 64) {
        int hh = tid >> 6, j = tid & 63;
        float x1 = bf2f(row[QDIM + hh * HD + j]);
        float x2 = bf2f(row[QDIM + hh * HD + j + 64]);
        float c = cosv[j], s = sinv[j];
        kr[(size_t)t * KVDIM + hh * HD + j]      = f2bf(x1 * c - x2 * s);
        kr[(size_t)t * KVDIM + hh * HD + j + 64] = f2bf(x2 * c + x1 * s);
    }
}

// ---------------------------------------------------------------------------
// K2b: V transpose: qkvb bf16 V-section -> vt bf16 [KVDIM][T].
// ---------------------------------------------------------------------------
__global__ __launch_bounds__(256) void v_transpose(
    const unsigned short* __restrict__ qkvb,
    unsigned short* __restrict__ vt)
{
    __shared__ unsigned short tile[64][72];
    const int tid = threadIdx.x;
    const int t0  = blockIdx.x * 64;
    const int d0  = blockIdx.y * 64;

    {
        int r = tid >> 2;
        int c = (tid & 3) * 16;
        const unsigned short* src =
            &qkvb[(size_t)(t0 + r) * QKVDIM + QDIM + KVDIM + d0 + c];
        *reinterpret_cast<u16x8*>(&tile[r][c])     = *reinterpret_cast<const u16x8*>(src);
        *reinterpret_cast<u16x8*>(&tile[r][c + 8]) = *reinterpret_cast<const u16x8*>(src + 8);
    }
    __syncthreads();
    {
        int dr = tid >> 3;
        int tc = (tid & 7) * 8;
        #pragma unroll
        for (int i = 0; i < 2; i++) {
            int d = dr + i * 32;
            u16x8 ov;
            #pragma unroll
            for (int e = 0; e < 8; e++) ov[e] = tile[tc + e][d];
            *reinterpret_cast<u16x8*>(&vt[(size_t)(d0 + d) * T_TOK + t0 + tc]) = ov;
        }
    }
}

// ---------------------------------------------------------------------------
// K3: causal GQA flash attention, split-K (round-7 decomposition) +
// counted vmcnt(8) staging + exp2 softmax (Q pre-scaled) + diagonal-only
// masking + HW bf16 converts.
// ---------------------------------------------------------------------------
__global__ __launch_bounds__(256) void attn_kernel(
    const unsigned short* __restrict__ q,   // bf16 [T][NH*HD], pre-scaled
    const unsigned short* __restrict__ k,   // bf16 [T][NKV*HD]
    const unsigned short* __restrict__ vt,  // bf16 [KVDIM][T] (transposed)
    unsigned short* __restrict__ o,         // bf16 [T][NH*HD]
    float* __restrict__ pO,                 // fp32 [512][64][128] partials
    float* __restrict__ pML)                // fp32 [512][2][64]  (m, ell)
{
    __shared__ alignas(16) unsigned short Ks[2][64 * 128];
    __shared__ alignas(16) unsigned short Vs[2][128 * 64];
    __shared__ alignas(16) unsigned short P[4][16][72];

    const int tid  = threadIdx.x;
    const int lane = tid & 63;
    const int w    = tid >> 6;
    const int lg   = lane >> 4, lc = lane & 15;
    const int b    = blockIdx.x;
    const int h    = b & 15;
    const int idx  = b >> 4;                 // 0..47, LPT order

    int tau, c0;
    if (idx <= 16)      { tau = 15 + idx; c0 = 0; }
    else if (idx == 17) { tau = 31;       c0 = 1; }
    else {
        int j = idx - 18, kk = 15 - (j >> 1);
        if ((j & 1) == 0) { tau = kk - 1;  c0 = 0; }
        else              { tau = kk + 15; c0 = 1; }
    }
    const int kstart = c0 << 4;
    const int kcnt   = min(16, tau + 1 - kstart);

    const int q0   = tau * 64 + w * 16;
    const int hk   = h >> 3;
    const int xr   = (lc & 7) << 4;

    const int krow_l = (lane >> 4);
    const int kgS    = (lane & 15);
    const int vrow_l = (lane >> 3);
    const int vgS    = (lane & 7);

    u16x8 qf[4];
    #pragma unroll
    for (int dc = 0; dc < 4; dc++)
        qf[dc] = *reinterpret_cast<const u16x8*>(
            &q[(size_t)(q0 + lc) * QDIM + h * HD + dc * 32 + lg * 8]);

    float mrow = -1e30f, ell = 0.f;          // log2 units
    f32x4 oacc[8] = {};

    auto stage = [&](int buf, int kb) {
        #pragma unroll
        for (int ci = 0; ci < 4; ci++) {
            const int chunk = w * 4 + ci;
            const int row   = chunk * 4 + krow_l;
            const int gSk   = kgS ^ (row & 7);
            const unsigned short* gp =
                &k[(size_t)(kb + row) * KVDIM + hk * HD + gSk * 8];
            __builtin_amdgcn_global_load_lds(
                (const __attribute__((address_space(1))) void*)gp,
                (__attribute__((address_space(3))) void*)(&Ks[buf][chunk * 512]),
                16, 0, 0);
        }
        #pragma unroll
        for (int ci = 0; ci < 4; ci++) {
            const int chunk = w * 4 + ci;
            const int dr    = chunk * 8 + vrow_l;
            const int gSv   = vgS ^ (dr & 7);
            const unsigned short* gp =
                &vt[(size_t)(hk * HD + dr) * T_TOK + kb + gSv * 8];
            __builtin_amdgcn_global_load_lds(
                (const __attribute__((address_space(1))) void*)gp,
                (__attribute__((address_space(3))) void*)(&Vs[buf][chunk * 512]),
                16, 0, 0);
        }
    };

    stage(0, kstart * 64);
    for (int it = 0; it < kcnt; ++it) {
        if (it + 1 < kcnt) {
            stage((it + 1) & 1, (kstart + it + 1) * 64);
            asm volatile("s_waitcnt vmcnt(8)" ::: "memory");   // stage(it) done
        } else {
            asm volatile("s_waitcnt vmcnt(0)" ::: "memory");
        }
        __syncthreads();

        const int kb = (kstart + it) * 64;
        const char* KsB = (const char*)Ks[it & 1];
        const char* VsB = (const char*)Vs[it & 1];

        // swapped QK^T (Q pre-scaled): lane owns q-row q0+lc, 16 k-scores
        float sc[4][4];
        const bool dia = (kb + 63 > q0);     // wave-uniform
        #pragma unroll
        for (int c4 = 0; c4 < 4; c4++) {
            const int row = c4 * 16 + lc;
            f32x4 s = {0.f, 0.f, 0.f, 0.f};
            #pragma unroll
            for (int dc = 0; dc < 4; dc++) {
                u16x8 kf = *reinterpret_cast<const u16x8*>(
                    KsB + row * 256 + ((dc * 64 + lg * 16) ^ xr));
                s = mfma16(kf, qf[dc], s);   // SWAPPED: A=K, B=Q
            }
            if (dia) {
                #pragma unroll
                for (int j = 0; j < 4; j++) {
                    const int kpos = kb + c4 * 16 + lg * 4 + j;
                    sc[c4][j] = (kpos <= q0 + lc) ? s[j] : -1e30f;
                }
            } else {
                #pragma unroll
                for (int j = 0; j < 4; j++) sc[c4][j] = s[j];
            }
        }

        float t01 = fmaxf(fmaxf(sc[0][0], sc[0][1]), fmaxf(sc[0][2], sc[0][3]));
        float t23 = fmaxf(fmaxf(sc[1][0], sc[1][1]), fmaxf(sc[1][2], sc[1][3]));
        float t45 = fmaxf(fmaxf(sc[2][0], sc[2][1]), fmaxf(sc[2][2], sc[2][3]));
        float t67 = fmaxf(fmaxf(sc[3][0], sc[3][1]), fmaxf(sc[3][2], sc[3][3]));
        float tmx = fmaxf(fmaxf(t01, t23), fmaxf(t45, t67));
        tmx = fmaxf(tmx, __shfl_xor(tmx, 16));
        tmx = fmaxf(tmx, __shfl_xor(tmx, 32));

        float mn;
        if (__all(tmx <= mrow + DEFER_THR)) {   // defer-max (T13)
            mn = mrow;
        } else {
            mn = fmaxf(mrow, tmx);
            float alpha = __builtin_amdgcn_exp2f(mrow - mn);
            mrow = mn;
            ell *= alpha;
            float aj[4];
            #pragma unroll
            for (int j = 0; j < 4; j++)
                aj[j] = __shfl(alpha, lg * 4 + j);
            #pragma unroll
            for (int d8 = 0; d8 < 8; d8++)
                #pragma unroll
                for (int j = 0; j < 4; j++)
                    oacc[d8][j] *= aj[j];
        }

        float rs = 0.f;
        #pragma unroll
        for (int c4 = 0; c4 < 4; c4++) {
            float p0 = __builtin_amdgcn_exp2f(sc[c4][0] - mn);
            float p1 = __builtin_amdgcn_exp2f(sc[c4][1] - mn);
            float p2 = __builtin_amdgcn_exp2f(sc[c4][2] - mn);
            float p3 = __builtin_amdgcn_exp2f(sc[c4][3] - mn);
            rs += (p0 + p1) + (p2 + p3);
            ushort4 pk;
            pk.x = f2bf(p0); pk.y = f2bf(p1); pk.z = f2bf(p2); pk.w = f2bf(p3);
            *reinterpret_cast<ushort4*>(&P[w][lc][c4 * 16 + lg * 4]) = pk;
        }
        rs += __shfl_xor(rs, 16);
        rs += __shfl_xor(rs, 32);
        ell += rs;

        asm volatile("s_waitcnt lgkmcnt(0)" ::: "memory");
        __builtin_amdgcn_sched_barrier(0);

        u16x8 pf0 = *reinterpret_cast<const u16x8*>(&P[w][lc][lg * 8]);
        u16x8 pf1 = *reinterpret_cast<const u16x8*>(&P[w][lc][32 + lg * 8]);

        #pragma unroll
        for (int d8 = 0; d8 < 8; d8++) {
            const int drow = d8 * 16 + lc;
            u16x8 vf0 = *reinterpret_cast<const u16x8*>(
                VsB + drow * 128 + ((lg * 16) ^ xr));
            u16x8 vf1 = *reinterpret_cast<const u16x8*>(
                VsB + drow * 128 + ((lg * 16 + 64) ^ xr));
            oacc[d8] = mfma16(pf0, vf0, oacc[d8]);
            oacc[d8] = mfma16(pf1, vf1, oacc[d8]);
        }
        __syncthreads();
    }

    if (tau < 16) {
        float ej[4];
        #pragma unroll
        for (int j = 0; j < 4; j++)
            ej[j] = __shfl(ell, lg * 4 + j);
        #pragma unroll
        for (int d8 = 0; d8 < 8; d8++)
            #pragma unroll
            for (int j = 0; j < 4; j++) {
                float val = oacc[d8][j] / ej[j];
                o[(size_t)(q0 + lg * 4 + j) * QDIM + h * HD + d8 * 16 + lc] = f2bf(val);
            }
    } else {
        const int s = (h * 16 + (tau - 16)) * 2 + c0;
        float* po = pO + (size_t)s * 8192;
        #pragma unroll
        for (int d8 = 0; d8 < 8; d8++)
            #pragma unroll
            for (int j = 0; j < 4; j++)
                po[(w * 16 + lg * 4 + j) * 128 + d8 * 16 + lc] = oacc[d8][j];
        if (lg == 0) {
            pML[s * 128 + w * 16 + lc]      = mrow;
            pML[s * 128 + 64 + w * 16 + lc] = ell;
        }
    }
}

// ---------------------------------------------------------------------------
// K3b: combine two split-K partials (m in log2 units) -> bf16 output.
// ---------------------------------------------------------------------------
__global__ __launch_bounds__(256) void attn_combine(
    const float* __restrict__ pO,
    const float* __restrict__ pML,
    unsigned short* __restrict__ o)
{
    const int b  = blockIdx.x;
    const int h  = b >> 4, ti = b & 15;
    const int tau = 16 + ti;
    const int s0 = (h * 16 + ti) * 2, s1 = s0 + 1;

    const int tid = threadIdx.x;
    const int r   = tid >> 2;
    const int cg  = (tid & 3) * 32;

    const float m1 = pML[s0 * 128 + r],      m2 = pML[s1 * 128 + r];
    const float l1 = pML[s0 * 128 + 64 + r], l2 = pML[s1 * 128 + 64 + r];
    const float M  = fmaxf(m1, m2);
    const float w1 = __builtin_amdgcn_exp2f(m1 - M);
    const float w2 = __builtin_amdgcn_exp2f(m2 - M);
    const float rn = 1.0f / (w1 * l1 + w2 * l2);

    const float* o1 = pO + (size_t)s0 * 8192 + r * 128 + cg;
    const float* o2 = pO + (size_t)s1 * 8192 + r * 128 + cg;
    unsigned short* dst = o + (size_t)(tau * 64 + r) * QDIM + h * HD + cg;

    #pragma unroll
    for (int i = 0; i < 8; i++) {
        float4 a = *reinterpret_cast<const float4*>(o1 + i * 4);
        float4 c = *reinterpret_cast<const float4*>(o2 + i * 4);
        ushort4 pk;
        pk.x = f2bf((w1 * a.x + w2 * c.x) * rn);
        pk.y = f2bf((w1 * a.y + w2 * c.y) * rn);
        pk.z = f2bf((w1 * a.z + w2 * c.z) * rn);
        pk.w = f2bf((w1 * a.w + w2 * c.w) * rn);
        *reinterpret_cast<ushort4*>(dst + i * 4) = pk;
    }
}

// ---------------------------------------------------------------------------
extern "C" void kernel_launch(void* const* d_in, const int* in_sizes, int n_in,
                              void* d_out, int out_size, void* d_ws, size_t ws_size,
                              hipStream_t stream) {
    const float* hidden    = (const float*)d_in[0];
    const int*   positions = (const int*)d_in[1];
    const float* Wq        = (const float*)d_in[2];
    const float* Wk        = (const float*)d_in[3];
    const float* Wv        = (const float*)d_in[4];
    const float* Wo        = (const float*)d_in[5];
    float*       out       = (float*)d_out;

    char* ws = (char*)d_ws;
    unsigned short* qkvb = (unsigned short*)(ws);           // bf16 [T][2560], 10485760 B
    unsigned short* qr  = (unsigned short*)(ws + 20971520); // 8388608 B
    unsigned short* kr  = (unsigned short*)(ws + 29360128); // 1048576 B
    unsigned short* vt  = (unsigned short*)(ws + 30408704); // 1048576 B
    unsigned short* att = (unsigned short*)(ws + 31457280); // 8388608 B
    unsigned short* hb  = (unsigned short*)(ws + 39845888); // 8388608 B
    unsigned short* Wf  = (unsigned short*)(ws + 48234496); // 10485760 B
    unsigned short* Wob = (unsigned short*)(ws + 58720256); // 8388608 B
    // split-K partials alias qkvb (dead after rope+v_transpose):
    float* pO  = (float*)(ws);              // 16777216 B
    float* pML = (float*)(ws + 16777216);   //   262144 B (< 20971520)

    pack_bf16_all<<<6656, 256, 0, stream>>>(hidden, Wq, Wk, Wv, Wo, hb, Wf, Wob);
    gemm_bf16<true><<<320, 256, 0, stream>>>(hb, Wf, qkvb, HID, QKVDIM, QKVDIM / 128);
    rope_kernel<<<T_TOK, 256, 0, stream>>>(qkvb, positions, qr, kr);
    v_transpose<<<dim3(T_TOK / 64, KVDIM / 64), 256, 0, stream>>>(qkvb, vt);
    attn_kernel<<<NH * 48, 256, 0, stream>>>(qr, kr, vt, att, pO, pML);
    attn_combine<<<256, 256, 0, stream>>>(pO, pML, att);
    gemm_bf16<false><<<256, 256, 0, stream>>>(att, Wob, out, QDIM, HID, HID / 128);
}